// Round 10
// baseline (484.439 us; speedup 1.0000x reference)
//
#include <hip/hip_runtime.h>
#include <hip/hip_bf16.h>

typedef __bf16 bf16;
typedef __bf16 bf16x4 __attribute__((ext_vector_type(4)));
typedef __bf16 bf16x8 __attribute__((ext_vector_type(8)));
typedef float floatx4 __attribute__((ext_vector_type(4)));
typedef float float4v __attribute__((ext_vector_type(4)));

#define MFMA16(a, b, c) __builtin_amdgcn_mfma_f32_16x16x32_bf16(a, b, c, 0, 0, 0)

constexpr int B_ = 2, S_ = 2048, DIM_ = 1024, H_ = 16, HD_ = 64;
constexpr float SCALE_ = 0.125f;   // HD^-0.5
constexpr float EPS_ = 1e-8f;

// ---------------------------------------------------------------- helpers
__device__ __forceinline__ void gload_lds16(const void* g, void* l) {
    __builtin_amdgcn_global_load_lds(
        (const __attribute__((address_space(1))) void*)g,
        (__attribute__((address_space(3))) void*)l, 16, 0, 0);
}

// ---------------------------------------------------------------- f32 -> bf16
__global__ __launch_bounds__(256) void cvt_kernel(const float* __restrict__ in,
                                                  bf16* __restrict__ out, int n4) {
    int i = blockIdx.x * 256 + threadIdx.x;
    if (i >= n4) return;
    float4v v = ((const float4v*)in)[i];
    bf16x4 o;
    o[0] = (bf16)v[0]; o[1] = (bf16)v[1]; o[2] = (bf16)v[2]; o[3] = (bf16)v[3];
    ((bf16x4*)out)[i] = o;
}

// ---------------------------------------------------------------- lp = bf16(mask + ln(clip(prior)))
__global__ __launch_bounds__(256) void lp_kernel(const float* __restrict__ mask,
                                                 const float* __restrict__ prior,
                                                 bf16* __restrict__ lp, int n4) {
    int i = blockIdx.x * 256 + threadIdx.x;
    if (i >= n4) return;
    float4v m = ((const float4v*)mask)[i];
    float4v p = ((const float4v*)prior)[i];
    bf16x4 o;
#pragma unroll
    for (int j = 0; j < 4; ++j) o[j] = (bf16)(m[j] + __logf(fmaxf(p[j], EPS_)));
    ((bf16x4*)lp)[i] = o;
}

// ---------------------------------------------------------------- GEMM C = A(MxK) * B(NxK)^T
template<int OUTF32, int BIASED>
__global__ __launch_bounds__(256) void gemm_bt(const bf16* __restrict__ A,
                                               const bf16* __restrict__ B,
                                               void* __restrict__ Cp,
                                               const float* __restrict__ bias,
                                               int M, int N, int K) {
    __shared__ bf16 As[128 * 64];
    __shared__ bf16 Bs[128 * 64];
    const int lane = threadIdx.x & 63, wid = threadIdx.x >> 6;
    const int colL = lane & 15, grp = lane >> 4;
    const int bm = blockIdx.y * 128, bn = blockIdx.x * 128;
    const int wr = wid >> 1, wc = wid & 1;

    floatx4 acc[4][4];
#pragma unroll
    for (int m = 0; m < 4; ++m)
#pragma unroll
        for (int n = 0; n < 4; ++n) acc[m][n] = (floatx4){0.f, 0.f, 0.f, 0.f};

    for (int k0 = 0; k0 < K; k0 += 64) {
#pragma unroll
        for (int i = 0; i < 4; ++i) {
            int c = wid * 256 + i * 64 + lane;
            int row = c >> 3, sub = c & 7;
            gload_lds16(A + (size_t)(bm + row) * K + k0 + sub * 8,
                        &As[(wid * 256 + i * 64) * 8]);
            gload_lds16(B + (size_t)(bn + row) * K + k0 + sub * 8,
                        &Bs[(wid * 256 + i * 64) * 8]);
        }
        __syncthreads();
#pragma unroll
        for (int ks = 0; ks < 2; ++ks) {
            bf16x8 af[4], bfr[4];
#pragma unroll
            for (int m = 0; m < 4; ++m)
                af[m] = *(const bf16x8*)(&As[(wr * 64 + m * 16 + colL) * 64 + ks * 32 + grp * 8]);
#pragma unroll
            for (int n = 0; n < 4; ++n)
                bfr[n] = *(const bf16x8*)(&Bs[(wc * 64 + n * 16 + colL) * 64 + ks * 32 + grp * 8]);
#pragma unroll
            for (int m = 0; m < 4; ++m)
#pragma unroll
                for (int n = 0; n < 4; ++n)
                    acc[m][n] = MFMA16(af[m], bfr[n], acc[m][n]);
        }
        __syncthreads();
    }

#pragma unroll
    for (int m = 0; m < 4; ++m)
#pragma unroll
        for (int n = 0; n < 4; ++n)
#pragma unroll
            for (int r = 0; r < 4; ++r) {
                int row = bm + wr * 64 + m * 16 + grp * 4 + r;
                int col = bn + wc * 64 + n * 16 + colL;
                float v = acc[m][n][r];
                if (BIASED) v += bias[col];
                if (OUTF32) ((float*)Cp)[(size_t)row * N + col] = v;
                else        ((bf16*)Cp)[(size_t)row * N + col] = (bf16)v;
            }
}

// ---------------------------------------------------------------- RoPE (+scale), (B,S,DIM-slice) -> (B,H,S,HD)
__global__ __launch_bounds__(256) void rope_kernel(const bf16* __restrict__ in,
                                                   const float* __restrict__ fr,
                                                   bf16* __restrict__ out,
                                                   int in_ld, float scale) {
    int tid = blockIdx.x * 256 + threadIdx.x;
    int j = tid & 7, h = (tid >> 3) & 15, s = (tid >> 7) & 2047, b = tid >> 18;
    bf16x8 x = *(const bf16x8*)(in + (size_t)(b * 2048 + s) * in_ld + h * 64 + j * 8);
    const float* f = fr + (size_t)(b * 2048 + s) * 64 + j * 4;
    bf16x8 o;
#pragma unroll
    for (int i = 0; i < 4; ++i) {
        float c = f[i], sn = f[32 + i];
        float x0 = (float)x[2 * i], x1 = (float)x[2 * i + 1];
        o[2 * i]     = (bf16)((x0 * c - x1 * sn) * scale);
        o[2 * i + 1] = (bf16)((x0 * sn + x1 * c) * scale);
    }
    *(bf16x8*)(out + ((size_t)(b * 16 + h) * 2048 + s) * 64 + j * 8) = o;
}

// ---------------------------------------------------------------- V transpose: KVp(B,S,2048) v-part -> Vt(B,H,HD,S)
__global__ __launch_bounds__(256) void vtrans_kernel(const bf16* __restrict__ KVp,
                                                     bf16* __restrict__ Vt) {
    int bid = blockIdx.x;
    int sb = bid & 31, h = (bid >> 5) & 15, b = bid >> 9;
    __shared__ bf16 tile[64][66];
    int tid = threadIdx.x;
#pragma unroll
    for (int i = 0; i < 2; ++i) {
        int c = tid + i * 256;
        int row = c >> 3, sub = c & 7;
        bf16x8 x = *(const bf16x8*)(KVp + (size_t)(b * 2048 + sb * 64 + row) * 2048
                                    + 1024 + h * 64 + sub * 8);
#pragma unroll
        for (int k = 0; k < 8; ++k) tile[row][sub * 8 + k] = x[k];
    }
    __syncthreads();
#pragma unroll
    for (int i = 0; i < 2; ++i) {
        int c = tid + i * 256;
        int drow = c >> 3, sub = c & 7;
        bf16x8 o;
#pragma unroll
        for (int k = 0; k < 8; ++k) o[k] = tile[sub * 8 + k][drow];
        *(bf16x8*)(Vt + ((size_t)(b * 16 + h) * 64 + drow) * 2048 + sb * 64 + sub * 8) = o;
    }
}

// ---------------------------------------------------------------- fused attention, two-phase, shift-free
// Block = (b,h,64 q rows), 4 waves x 16 q rows. Proven one-barrier-per-tile,
// all-dbuf schedule (R6): stages for tile kt+1 issued at start of tile kt into
// the other buffer, drained by the end-of-tile barrier. K + bf16-LP staged in
// LDS; V direct global->reg (L1 broadcast across waves). 49.4 KB -> 3 blocks/CU.
__global__ __launch_bounds__(256, 3) void attn_fused(const bf16* __restrict__ Qr,
                                                     const bf16* __restrict__ Kr,
                                                     const bf16* __restrict__ Vt,
                                                     const bf16* __restrict__ lp,
                                                     float* __restrict__ attn_out,
                                                     bf16* __restrict__ O) {
    __shared__ bf16 KB[2][4096];        // 16 KB dbuf
    __shared__ bf16 LPB[2][4096];       // 16 KB dbuf (64 x 64 bf16 per buffer)
    union ShU {
        bf16 P[4][1024];                //  8 KB phase 1 (wave-private)
        float FS[4][1088];              // 17.4 KB phase 2 (wave-private)
    };
    __shared__ ShU sm;

    const int tid = threadIdx.x;
    const int lane = tid & 63, wv = tid >> 6;
    const int colL = lane & 15, grp = lane >> 4;
    // XCD swizzle: all 16 heads of a (b,qb) pair on one XCD
    const int n = blockIdx.x;
    const int x = n & 7, j = n >> 3;
    const int h = j & 15;
    const int pp = (j >> 4) * 8 + x;
    const int b = pp >> 5, qb = pp & 31;
    const int bh = b * H_ + h;
    const int q0 = qb * 64 + wv * 16;
    const int rowL = wv * 16 + colL;        // block-level q-row (0..63)

    const bf16* Qbase = Qr + ((size_t)bh * S_ + q0) * HD_;
    const bf16* Kbase = Kr + (size_t)bh * S_ * HD_;
    const bf16* Vbase = Vt + (size_t)bh * HD_ * S_;
    const bf16* LPbase = lp + ((size_t)b * S_ + qb * 64) * S_;

    bf16x8 qf0 = *(const bf16x8*)(Qbase + (size_t)colL * HD_ + grp * 8);
    bf16x8 qf1 = *(const bf16x8*)(Qbase + (size_t)colL * HD_ + 32 + grp * 8);

    bf16* P = sm.P[wv];
    const int swz = (colL & 7) << 3;
    const int c7 = colL & 7;
    const int r7 = rowL & 7;

    auto stageK = [&](int buf, int k0) {
#pragma unroll
        for (int i = 0; i < 2; ++i) {
            int c = i * 256 + tid;
            int row = c >> 3, sub = c & 7;
            gload_lds16(Kbase + (size_t)(k0 + row) * HD_ + ((sub ^ (row & 7)) << 3),
                        &KB[buf][(c & ~63) << 3]);
        }
    };
    // LP tile: 64 rows x 64 bf16 (8 KB) = 512 x 16B chunks, XOR-swizzled source
    auto stageLP = [&](int buf, int k0) {
#pragma unroll
        for (int i = 0; i < 2; ++i) {
            int c = i * 256 + tid;
            int row = c >> 3, sub = c & 7;
            gload_lds16(LPbase + (size_t)row * S_ + k0 + ((sub ^ (row & 7)) << 3),
                        &LPB[buf][(c & ~63) << 3]);
        }
    };
    // lane's lp for sub-tile ct: cols ct*16 + grp*4 .. +3 of row rowL
    auto lpRead = [&](int cur, int ct) -> float4v {
        int chunk = ct * 2 + (grp >> 1);
        bf16x4 v = *(const bf16x4*)&LPB[cur][rowL * 64 + ((chunk ^ r7) << 3) + ((grp & 1) << 2)];
        float4v f;
#pragma unroll
        for (int r = 0; r < 4; ++r) f[r] = (float)v[r];
        return f;
    };
    auto qk = [&](floatx4* s, int cur) {
#pragma unroll
        for (int ct = 0; ct < 4; ++ct) {
            const int r8 = (ct * 16 + colL) * 8;
            bf16x8 a0 = *(const bf16x8*)&KB[cur][(r8 + (grp ^ c7)) * 8];
            bf16x8 a1 = *(const bf16x8*)&KB[cur][(r8 + (grp ^ 4 ^ c7)) * 8];
            floatx4 acc = (floatx4){0.f, 0.f, 0.f, 0.f};
            acc = MFMA16(a0, qf0, acc);
            acc = MFMA16(a1, qf1, acc);
            s[ct] = acc;
        }
    };

    float ua = 0.f;
    floatx4 oT[4];
#pragma unroll
    for (int dt = 0; dt < 4; ++dt) oT[dt] = (floatx4){0.f, 0.f, 0.f, 0.f};

    // ---------------- phase 1 prologue
    stageK(0, 0);
    stageLP(0, 0);
    __syncthreads();

    // ---------------- phase 1: U + O accumulation (one barrier per tile)
    for (int kt = 0; kt < 32; ++kt) {
        const int k0 = kt * 64;
        const int cur = kt & 1;
        if (kt < 31) { stageK(cur ^ 1, k0 + 64); stageLP(cur ^ 1, k0 + 64); }

        // V for current tile: direct global -> reg (broadcast across waves)
        bf16x8 vf[2][4];
#pragma unroll
        for (int ks = 0; ks < 2; ++ks)
#pragma unroll
            for (int dt = 0; dt < 4; ++dt)
                vf[ks][dt] = *(const bf16x8*)(Vbase + (size_t)(dt * 16 + colL) * S_
                                              + k0 + ks * 32 + grp * 8);

        floatx4 s[4];
        qk(s, cur);

        // t = exp(s + lp) -> P, accumulate ua
#pragma unroll
        for (int ct = 0; ct < 4; ++ct) {
            float4v lv = lpRead(cur, ct);
            bf16x4 pw;
#pragma unroll
            for (int r = 0; r < 4; ++r) {
                float tv = __expf(s[ct][r] + lv[r]);
                ua += tv;
                pw[r] = (bf16)tv;
            }
            *(bf16x4*)&P[(colL * 64 + ct * 16 + grp * 4) ^ swz] = pw;
        }
        // PV from vf regs
#pragma unroll
        for (int ks = 0; ks < 2; ++ks) {
            bf16x8 pb = *(const bf16x8*)&P[(colL * 64 + ks * 32 + grp * 8) ^ swz];
#pragma unroll
            for (int dt = 0; dt < 4; ++dt)
                oT[dt] = MFMA16(vf[ks][dt], pb, oT[dt]);
        }
        __syncthreads();
    }

    // ---------------- U reduce + O write
    ua += __shfl_xor(ua, 16, 64);
    ua += __shfl_xor(ua, 32, 64);
    const float iu = 1.0f / ua;
#pragma unroll
    for (int dt = 0; dt < 4; ++dt) {
        bf16x4 ow;
#pragma unroll
        for (int r = 0; r < 4; ++r) ow[r] = (bf16)(oT[dt][r] * iu);
        *(bf16x4*)(O + ((size_t)b * S_ + q0 + colL) * DIM_ + h * HD_ + dt * 16 + grp * 4) = ow;
    }

    // ---------------- phase 2 prologue (KB[0]/LPB[0] last read 2 barriers ago)
    stageK(0, 0);
    stageLP(0, 0);
    __syncthreads();

    // ---------------- phase 2: recompute, write attn = exp(s+lp)*invU
    const float* Aout = attn_out + (size_t)bh * S_ * S_;
    for (int kt = 0; kt < 32; ++kt) {
        const int k0 = kt * 64;
        const int cur = kt & 1;
        if (kt < 31) { stageK(cur ^ 1, k0 + 64); stageLP(cur ^ 1, k0 + 64); }

        floatx4 s[4];
        qk(s, cur);

        // f32 tile into wave-private FS (row = q-in-wave, col = k-in-tile)
#pragma unroll
        for (int ct = 0; ct < 4; ++ct) {
            float4v lv = lpRead(cur, ct);
            float4v o;
#pragma unroll
            for (int r = 0; r < 4; ++r) o[r] = __expf(s[ct][r] + lv[r]) * iu;
            *(float4v*)&sm.FS[wv][colL * 68 + ct * 16 + grp * 4] = o;
        }
        // transposed read-out: 4 rows x 256B contiguous per instruction
#pragma unroll
        for (int it = 0; it < 4; ++it) {
            const int row = it * 4 + grp;
            float4v v = *(const float4v*)&sm.FS[wv][row * 68 + colL * 4];
            *(float4v*)(Aout + (size_t)(q0 + row) * S_ + k0 + colL * 4) = v;
        }
        __syncthreads();
    }
}

// ---------------------------------------------------------------- launch
extern "C" void kernel_launch(void* const* d_in, const int* in_sizes, int n_in,
                              void* d_out, int out_size, void* d_ws, size_t ws_size,
                              hipStream_t stream) {
    const float* q_x   = (const float*)d_in[0];
    const float* kv_x  = (const float*)d_in[1];
    const float* q_fr  = (const float*)d_in[2];
    const float* k_fr  = (const float*)d_in[3];
    const float* maskp = (const float*)d_in[4];
    const float* prior = (const float*)d_in[5];
    const float* Wq    = (const float*)d_in[6];
    const float* Wkv   = (const float*)d_in[7];
    const float* Wproj = (const float*)d_in[8];
    const float* bproj = (const float*)d_in[9];

    float* out_x    = (float*)d_out;                       // (B,S,DIM)
    float* out_attn = out_x + (size_t)B_ * S_ * DIM_;      // (B,H,S,S)

    char* w = (char*)d_ws;
    bf16* qx_b  = (bf16*)(w + (size_t)0);          //  8 MiB
    bf16* kvx_b = (bf16*)(w + ((size_t)8  << 20)); //  8 MiB
    bf16* wq_b  = (bf16*)(w + ((size_t)16 << 20)); //  2 MiB
    bf16* wkv_b = (bf16*)(w + ((size_t)18 << 20)); //  4 MiB
    bf16* wpj_b = (bf16*)(w + ((size_t)22 << 20)); //  2 MiB
    bf16* qp    = (bf16*)(w + ((size_t)24 << 20)); //  8 MiB  (B,S,DIM)
    bf16* kvp   = (bf16*)(w + ((size_t)32 << 20)); // 16 MiB  (B,S,2*DIM)
    bf16* qr    = (bf16*)(w + ((size_t)48 << 20)); //  8 MiB  (B,H,S,HD)
    bf16* kr    = (bf16*)(w + ((size_t)56 << 20)); //  8 MiB
    bf16* vt    = (bf16*)(w + ((size_t)64 << 20)); //  8 MiB  (B,H,HD,S)
    bf16* ob    = (bf16*)(w + ((size_t)72 << 20)); //  8 MiB  (B,S,DIM)
    bf16* lpb   = (bf16*)(w + ((size_t)96 << 20)); // 16 MiB  (B,S,S) bf16

    // f32 -> bf16 conversions + lp precompute
    cvt_kernel<<<4096, 256, 0, stream>>>(q_x,   qx_b,  1048576);
    cvt_kernel<<<4096, 256, 0, stream>>>(kv_x,  kvx_b, 1048576);
    cvt_kernel<<<1024, 256, 0, stream>>>(Wq,    wq_b,   262144);
    cvt_kernel<<<2048, 256, 0, stream>>>(Wkv,   wkv_b,  524288);
    cvt_kernel<<<1024, 256, 0, stream>>>(Wproj, wpj_b,  262144);
    lp_kernel<<<8192, 256, 0, stream>>>(maskp, prior, lpb, 2097152);

    // projections
    gemm_bt<0, 0><<<dim3(8, 32),  256, 0, stream>>>(qx_b,  wq_b,  qp,  nullptr, 4096, 1024, 1024);
    gemm_bt<0, 0><<<dim3(16, 32), 256, 0, stream>>>(kvx_b, wkv_b, kvp, nullptr, 4096, 2048, 1024);

    // RoPE + layout
    rope_kernel<<<2048, 256, 0, stream>>>(qp,  q_fr, qr, 1024, SCALE_);
    rope_kernel<<<2048, 256, 0, stream>>>(kvp, k_fr, kr, 2048, 1.0f);
    vtrans_kernel<<<1024, 256, 0, stream>>>(kvp, vt);

    // fused attention: O + attn in one kernel (XCD-swizzled grid)
    attn_fused<<<1024, 256, 0, stream>>>(qr, kr, vt, lpb, out_attn, ob);

    // output projection
    gemm_bt<1, 1><<<dim3(8, 32), 256, 0, stream>>>(ob, wpj_b, out_x, bproj, 4096, 1024, 1024);
}

// Round 11
// 483.677 us; speedup vs baseline: 1.0016x; 1.0016x over previous
//
#include <hip/hip_runtime.h>
#include <hip/hip_bf16.h>

typedef __bf16 bf16;
typedef __bf16 bf16x4 __attribute__((ext_vector_type(4)));
typedef __bf16 bf16x8 __attribute__((ext_vector_type(8)));
typedef float floatx4 __attribute__((ext_vector_type(4)));
typedef float float4v __attribute__((ext_vector_type(4)));

#define MFMA16(a, b, c) __builtin_amdgcn_mfma_f32_16x16x32_bf16(a, b, c, 0, 0, 0)

constexpr int B_ = 2, S_ = 2048, DIM_ = 1024, H_ = 16, HD_ = 64;
constexpr float SCALE_ = 0.125f;   // HD^-0.5
constexpr float EPS_ = 1e-8f;

// ---------------------------------------------------------------- helpers
__device__ __forceinline__ void gload_lds16(const void* g, void* l) {
    __builtin_amdgcn_global_load_lds(
        (const __attribute__((address_space(1))) void*)g,
        (__attribute__((address_space(3))) void*)l, 16, 0, 0);
}

// ---------------------------------------------------------------- f32 -> bf16
__global__ __launch_bounds__(256) void cvt_kernel(const float* __restrict__ in,
                                                  bf16* __restrict__ out, int n4) {
    int i = blockIdx.x * 256 + threadIdx.x;
    if (i >= n4) return;
    float4v v = ((const float4v*)in)[i];
    bf16x4 o;
    o[0] = (bf16)v[0]; o[1] = (bf16)v[1]; o[2] = (bf16)v[2]; o[3] = (bf16)v[3];
    ((bf16x4*)out)[i] = o;
}

// ---------------------------------------------------------------- lp = bf16(mask + ln(clip(prior)))
__global__ __launch_bounds__(256) void lp_kernel(const float* __restrict__ mask,
                                                 const float* __restrict__ prior,
                                                 bf16* __restrict__ lp, int n4) {
    int i = blockIdx.x * 256 + threadIdx.x;
    if (i >= n4) return;
    float4v m = ((const float4v*)mask)[i];
    float4v p = ((const float4v*)prior)[i];
    bf16x4 o;
#pragma unroll
    for (int j = 0; j < 4; ++j) o[j] = (bf16)(m[j] + __logf(fmaxf(p[j], EPS_)));
    ((bf16x4*)lp)[i] = o;
}

// ---------------------------------------------------------------- GEMM C = A(MxK) * B(NxK)^T
template<int OUTF32, int BIASED>
__global__ __launch_bounds__(256) void gemm_bt(const bf16* __restrict__ A,
                                               const bf16* __restrict__ B,
                                               void* __restrict__ Cp,
                                               const float* __restrict__ bias,
                                               int M, int N, int K) {
    __shared__ bf16 As[128 * 64];
    __shared__ bf16 Bs[128 * 64];
    const int lane = threadIdx.x & 63, wid = threadIdx.x >> 6;
    const int colL = lane & 15, grp = lane >> 4;
    const int bm = blockIdx.y * 128, bn = blockIdx.x * 128;
    const int wr = wid >> 1, wc = wid & 1;

    floatx4 acc[4][4];
#pragma unroll
    for (int m = 0; m < 4; ++m)
#pragma unroll
        for (int n = 0; n < 4; ++n) acc[m][n] = (floatx4){0.f, 0.f, 0.f, 0.f};

    for (int k0 = 0; k0 < K; k0 += 64) {
#pragma unroll
        for (int i = 0; i < 4; ++i) {
            int c = wid * 256 + i * 64 + lane;
            int row = c >> 3, sub = c & 7;
            gload_lds16(A + (size_t)(bm + row) * K + k0 + sub * 8,
                        &As[(wid * 256 + i * 64) * 8]);
            gload_lds16(B + (size_t)(bn + row) * K + k0 + sub * 8,
                        &Bs[(wid * 256 + i * 64) * 8]);
        }
        __syncthreads();
#pragma unroll
        for (int ks = 0; ks < 2; ++ks) {
            bf16x8 af[4], bfr[4];
#pragma unroll
            for (int m = 0; m < 4; ++m)
                af[m] = *(const bf16x8*)(&As[(wr * 64 + m * 16 + colL) * 64 + ks * 32 + grp * 8]);
#pragma unroll
            for (int n = 0; n < 4; ++n)
                bfr[n] = *(const bf16x8*)(&Bs[(wc * 64 + n * 16 + colL) * 64 + ks * 32 + grp * 8]);
#pragma unroll
            for (int m = 0; m < 4; ++m)
#pragma unroll
                for (int n = 0; n < 4; ++n)
                    acc[m][n] = MFMA16(af[m], bfr[n], acc[m][n]);
        }
        __syncthreads();
    }

#pragma unroll
    for (int m = 0; m < 4; ++m)
#pragma unroll
        for (int n = 0; n < 4; ++n)
#pragma unroll
            for (int r = 0; r < 4; ++r) {
                int row = bm + wr * 64 + m * 16 + grp * 4 + r;
                int col = bn + wc * 64 + n * 16 + colL;
                float v = acc[m][n][r];
                if (BIASED) v += bias[col];
                if (OUTF32) ((float*)Cp)[(size_t)row * N + col] = v;
                else        ((bf16*)Cp)[(size_t)row * N + col] = (bf16)v;
            }
}

// ---------------------------------------------------------------- RoPE (+scale), (B,S,DIM-slice) -> (B,H,S,HD)
__global__ __launch_bounds__(256) void rope_kernel(const bf16* __restrict__ in,
                                                   const float* __restrict__ fr,
                                                   bf16* __restrict__ out,
                                                   int in_ld, float scale) {
    int tid = blockIdx.x * 256 + threadIdx.x;
    int j = tid & 7, h = (tid >> 3) & 15, s = (tid >> 7) & 2047, b = tid >> 18;
    bf16x8 x = *(const bf16x8*)(in + (size_t)(b * 2048 + s) * in_ld + h * 64 + j * 8);
    const float* f = fr + (size_t)(b * 2048 + s) * 64 + j * 4;
    bf16x8 o;
#pragma unroll
    for (int i = 0; i < 4; ++i) {
        float c = f[i], sn = f[32 + i];
        float x0 = (float)x[2 * i], x1 = (float)x[2 * i + 1];
        o[2 * i]     = (bf16)((x0 * c - x1 * sn) * scale);
        o[2 * i + 1] = (bf16)((x0 * sn + x1 * c) * scale);
    }
    *(bf16x8*)(out + ((size_t)(b * 16 + h) * 2048 + s) * 64 + j * 8) = o;
}

// ---------------------------------------------------------------- V transpose: KVp(B,S,2048) v-part -> Vt(B,H,HD,S)
__global__ __launch_bounds__(256) void vtrans_kernel(const bf16* __restrict__ KVp,
                                                     bf16* __restrict__ Vt) {
    int bid = blockIdx.x;
    int sb = bid & 31, h = (bid >> 5) & 15, b = bid >> 9;
    __shared__ bf16 tile[64][66];
    int tid = threadIdx.x;
#pragma unroll
    for (int i = 0; i < 2; ++i) {
        int c = tid + i * 256;
        int row = c >> 3, sub = c & 7;
        bf16x8 x = *(const bf16x8*)(KVp + (size_t)(b * 2048 + sb * 64 + row) * 2048
                                    + 1024 + h * 64 + sub * 8);
#pragma unroll
        for (int k = 0; k < 8; ++k) tile[row][sub * 8 + k] = x[k];
    }
    __syncthreads();
#pragma unroll
    for (int i = 0; i < 2; ++i) {
        int c = tid + i * 256;
        int drow = c >> 3, sub = c & 7;
        bf16x8 o;
#pragma unroll
        for (int k = 0; k < 8; ++k) o[k] = tile[sub * 8 + k][drow];
        *(bf16x8*)(Vt + ((size_t)(b * 16 + h) * 64 + drow) * 2048 + sb * 64 + sub * 8) = o;
    }
}

// ---------------------------------------------------------------- fused attention, two-phase, shift-free
// Block = (b,h,64 q rows), 4 waves x 16 q rows, one barrier per tile, all-dbuf.
// ISSUE ORDER (critical): V direct loads FIRST, then next-tile K/LP stages ->
// PV waits vmcnt(4) (V only), stages stay in flight across the whole tile.
// K + bf16-LP staged in LDS; 49.4 KB -> 3 blocks/CU.
__global__ __launch_bounds__(256, 3) void attn_fused(const bf16* __restrict__ Qr,
                                                     const bf16* __restrict__ Kr,
                                                     const bf16* __restrict__ Vt,
                                                     const bf16* __restrict__ lp,
                                                     float* __restrict__ attn_out,
                                                     bf16* __restrict__ O) {
    __shared__ bf16 KB[2][4096];        // 16 KB dbuf
    __shared__ bf16 LPB[2][4096];       // 16 KB dbuf (64 x 64 bf16 per buffer)
    union ShU {
        bf16 P[4][1024];                //  8 KB phase 1 (wave-private)
        float FS[4][1088];              // 17.4 KB phase 2 (wave-private)
    };
    __shared__ ShU sm;

    const int tid = threadIdx.x;
    const int lane = tid & 63, wv = tid >> 6;
    const int colL = lane & 15, grp = lane >> 4;
    // XCD swizzle: all 16 heads of a (b,qb) pair on one XCD
    const int n = blockIdx.x;
    const int x = n & 7, j = n >> 3;
    const int h = j & 15;
    const int pp = (j >> 4) * 8 + x;
    const int b = pp >> 5, qb = pp & 31;
    const int bh = b * H_ + h;
    const int q0 = qb * 64 + wv * 16;
    const int rowL = wv * 16 + colL;        // block-level q-row (0..63)

    const bf16* Qbase = Qr + ((size_t)bh * S_ + q0) * HD_;
    const bf16* Kbase = Kr + (size_t)bh * S_ * HD_;
    const bf16* Vbase = Vt + (size_t)bh * HD_ * S_;
    const bf16* LPbase = lp + ((size_t)b * S_ + qb * 64) * S_;

    bf16x8 qf0 = *(const bf16x8*)(Qbase + (size_t)colL * HD_ + grp * 8);
    bf16x8 qf1 = *(const bf16x8*)(Qbase + (size_t)colL * HD_ + 32 + grp * 8);

    bf16* P = sm.P[wv];
    const int swz = (colL & 7) << 3;
    const int c7 = colL & 7;
    const int r7 = rowL & 7;

    auto stageK = [&](int buf, int k0) {
#pragma unroll
        for (int i = 0; i < 2; ++i) {
            int c = i * 256 + tid;
            int row = c >> 3, sub = c & 7;
            gload_lds16(Kbase + (size_t)(k0 + row) * HD_ + ((sub ^ (row & 7)) << 3),
                        &KB[buf][(c & ~63) << 3]);
        }
    };
    // LP tile: 64 rows x 64 bf16 (8 KB) = 512 x 16B chunks, XOR-swizzled source
    auto stageLP = [&](int buf, int k0) {
#pragma unroll
        for (int i = 0; i < 2; ++i) {
            int c = i * 256 + tid;
            int row = c >> 3, sub = c & 7;
            gload_lds16(LPbase + (size_t)row * S_ + k0 + ((sub ^ (row & 7)) << 3),
                        &LPB[buf][(c & ~63) << 3]);
        }
    };
    // lane's lp for sub-tile ct: cols ct*16 + grp*4 .. +3 of row rowL
    auto lpRead = [&](int cur, int ct) -> float4v {
        int chunk = ct * 2 + (grp >> 1);
        bf16x4 v = *(const bf16x4*)&LPB[cur][rowL * 64 + ((chunk ^ r7) << 3) + ((grp & 1) << 2)];
        float4v f;
#pragma unroll
        for (int r = 0; r < 4; ++r) f[r] = (float)v[r];
        return f;
    };
    auto qk = [&](floatx4* s, int cur) {
#pragma unroll
        for (int ct = 0; ct < 4; ++ct) {
            const int r8 = (ct * 16 + colL) * 8;
            bf16x8 a0 = *(const bf16x8*)&KB[cur][(r8 + (grp ^ c7)) * 8];
            bf16x8 a1 = *(const bf16x8*)&KB[cur][(r8 + (grp ^ 4 ^ c7)) * 8];
            floatx4 acc = (floatx4){0.f, 0.f, 0.f, 0.f};
            acc = MFMA16(a0, qf0, acc);
            acc = MFMA16(a1, qf1, acc);
            s[ct] = acc;
        }
    };

    float ua = 0.f;
    floatx4 oT[4];
#pragma unroll
    for (int dt = 0; dt < 4; ++dt) oT[dt] = (floatx4){0.f, 0.f, 0.f, 0.f};

    // ---------------- phase 1 prologue
    stageK(0, 0);
    stageLP(0, 0);
    __syncthreads();

    // ---------------- phase 1: U + O accumulation (one barrier per tile)
    for (int kt = 0; kt < 32; ++kt) {
        const int k0 = kt * 64;
        const int cur = kt & 1;

        // V for current tile FIRST (oldest in vmcnt queue -> PV waits vmcnt(4),
        // leaving the next-tile stages in flight)
        bf16x8 vf[2][4];
#pragma unroll
        for (int ks = 0; ks < 2; ++ks)
#pragma unroll
            for (int dt = 0; dt < 4; ++dt)
                vf[ks][dt] = *(const bf16x8*)(Vbase + (size_t)(dt * 16 + colL) * S_
                                              + k0 + ks * 32 + grp * 8);
        // next-tile stages AFTER V
        if (kt < 31) { stageK(cur ^ 1, k0 + 64); stageLP(cur ^ 1, k0 + 64); }

        floatx4 s[4];
        qk(s, cur);

        // t = exp(s + lp) -> P, accumulate ua
#pragma unroll
        for (int ct = 0; ct < 4; ++ct) {
            float4v lv = lpRead(cur, ct);
            bf16x4 pw;
#pragma unroll
            for (int r = 0; r < 4; ++r) {
                float tv = __expf(s[ct][r] + lv[r]);
                ua += tv;
                pw[r] = (bf16)tv;
            }
            *(bf16x4*)&P[(colL * 64 + ct * 16 + grp * 4) ^ swz] = pw;
        }
        // PV from vf regs
#pragma unroll
        for (int ks = 0; ks < 2; ++ks) {
            bf16x8 pb = *(const bf16x8*)&P[(colL * 64 + ks * 32 + grp * 8) ^ swz];
#pragma unroll
            for (int dt = 0; dt < 4; ++dt)
                oT[dt] = MFMA16(vf[ks][dt], pb, oT[dt]);
        }
        __syncthreads();
    }

    // ---------------- U reduce + O write
    ua += __shfl_xor(ua, 16, 64);
    ua += __shfl_xor(ua, 32, 64);
    const float iu = 1.0f / ua;
#pragma unroll
    for (int dt = 0; dt < 4; ++dt) {
        bf16x4 ow;
#pragma unroll
        for (int r = 0; r < 4; ++r) ow[r] = (bf16)(oT[dt][r] * iu);
        *(bf16x4*)(O + ((size_t)b * S_ + q0 + colL) * DIM_ + h * HD_ + dt * 16 + grp * 4) = ow;
    }

    // ---------------- phase 2 prologue
    stageK(0, 0);
    stageLP(0, 0);
    __syncthreads();

    // ---------------- phase 2: recompute, write attn = exp(s+lp)*invU
    const float* Aout = attn_out + (size_t)bh * S_ * S_;
    for (int kt = 0; kt < 32; ++kt) {
        const int k0 = kt * 64;
        const int cur = kt & 1;
        if (kt < 31) { stageK(cur ^ 1, k0 + 64); stageLP(cur ^ 1, k0 + 64); }

        floatx4 s[4];
        qk(s, cur);

        // f32 tile into wave-private FS (row = q-in-wave, col = k-in-tile)
#pragma unroll
        for (int ct = 0; ct < 4; ++ct) {
            float4v lv = lpRead(cur, ct);
            float4v o;
#pragma unroll
            for (int r = 0; r < 4; ++r) o[r] = __expf(s[ct][r] + lv[r]) * iu;
            *(float4v*)&sm.FS[wv][colL * 68 + ct * 16 + grp * 4] = o;
        }
        // transposed read-out: 4 rows x 256B contiguous per instruction
#pragma unroll
        for (int it = 0; it < 4; ++it) {
            const int row = it * 4 + grp;
            float4v v = *(const float4v*)&sm.FS[wv][row * 68 + colL * 4];
            *(float4v*)(Aout + (size_t)(q0 + row) * S_ + k0 + colL * 4) = v;
        }
        __syncthreads();
    }
}

// ---------------------------------------------------------------- launch
extern "C" void kernel_launch(void* const* d_in, const int* in_sizes, int n_in,
                              void* d_out, int out_size, void* d_ws, size_t ws_size,
                              hipStream_t stream) {
    const float* q_x   = (const float*)d_in[0];
    const float* kv_x  = (const float*)d_in[1];
    const float* q_fr  = (const float*)d_in[2];
    const float* k_fr  = (const float*)d_in[3];
    const float* maskp = (const float*)d_in[4];
    const float* prior = (const float*)d_in[5];
    const float* Wq    = (const float*)d_in[6];
    const float* Wkv   = (const float*)d_in[7];
    const float* Wproj = (const float*)d_in[8];
    const float* bproj = (const float*)d_in[9];

    float* out_x    = (float*)d_out;                       // (B,S,DIM)
    float* out_attn = out_x + (size_t)B_ * S_ * DIM_;      // (B,H,S,S)

    char* w = (char*)d_ws;
    bf16* qx_b  = (bf16*)(w + (size_t)0);          //  8 MiB
    bf16* kvx_b = (bf16*)(w + ((size_t)8  << 20)); //  8 MiB
    bf16* wq_b  = (bf16*)(w + ((size_t)16 << 20)); //  2 MiB
    bf16* wkv_b = (bf16*)(w + ((size_t)18 << 20)); //  4 MiB
    bf16* wpj_b = (bf16*)(w + ((size_t)22 << 20)); //  2 MiB
    bf16* qp    = (bf16*)(w + ((size_t)24 << 20)); //  8 MiB  (B,S,DIM)
    bf16* kvp   = (bf16*)(w + ((size_t)32 << 20)); // 16 MiB  (B,S,2*DIM)
    bf16* qr    = (bf16*)(w + ((size_t)48 << 20)); //  8 MiB  (B,H,S,HD)
    bf16* kr    = (bf16*)(w + ((size_t)56 << 20)); //  8 MiB
    bf16* vt    = (bf16*)(w + ((size_t)64 << 20)); //  8 MiB  (B,H,HD,S)
    bf16* ob    = (bf16*)(w + ((size_t)72 << 20)); //  8 MiB  (B,S,DIM)
    bf16* lpb   = (bf16*)(w + ((size_t)96 << 20)); // 16 MiB  (B,S,S) bf16

    // f32 -> bf16 conversions + lp precompute
    cvt_kernel<<<4096, 256, 0, stream>>>(q_x,   qx_b,  1048576);
    cvt_kernel<<<4096, 256, 0, stream>>>(kv_x,  kvx_b, 1048576);
    cvt_kernel<<<1024, 256, 0, stream>>>(Wq,    wq_b,   262144);
    cvt_kernel<<<2048, 256, 0, stream>>>(Wkv,   wkv_b,  524288);
    cvt_kernel<<<1024, 256, 0, stream>>>(Wproj, wpj_b,  262144);
    lp_kernel<<<8192, 256, 0, stream>>>(maskp, prior, lpb, 2097152);

    // projections
    gemm_bt<0, 0><<<dim3(8, 32),  256, 0, stream>>>(qx_b,  wq_b,  qp,  nullptr, 4096, 1024, 1024);
    gemm_bt<0, 0><<<dim3(16, 32), 256, 0, stream>>>(kvx_b, wkv_b, kvp, nullptr, 4096, 2048, 1024);

    // RoPE + layout
    rope_kernel<<<2048, 256, 0, stream>>>(qp,  q_fr, qr, 1024, SCALE_);
    rope_kernel<<<2048, 256, 0, stream>>>(kvp, k_fr, kr, 2048, 1.0f);
    vtrans_kernel<<<1024, 256, 0, stream>>>(kvp, vt);

    // fused attention: O + attn in one kernel (XCD-swizzled grid)
    attn_fused<<<1024, 256, 0, stream>>>(qr, kr, vt, lpb, out_attn, ob);

    // output projection
    gemm_bt<1, 1><<<dim3(8, 32), 256, 0, stream>>>(ob, wpj_b, out_x, bproj, 4096, 1024, 1024);
}

// Round 12
// 409.393 us; speedup vs baseline: 1.1833x; 1.1814x over previous
//
#include <hip/hip_runtime.h>
#include <hip/hip_bf16.h>

typedef __bf16 bf16;
typedef __bf16 bf16x4 __attribute__((ext_vector_type(4)));
typedef __bf16 bf16x8 __attribute__((ext_vector_type(8)));
typedef float floatx4 __attribute__((ext_vector_type(4)));
typedef float float4v __attribute__((ext_vector_type(4)));

#define MFMA16(a, b, c) __builtin_amdgcn_mfma_f32_16x16x32_bf16(a, b, c, 0, 0, 0)

constexpr int B_ = 2, S_ = 2048, DIM_ = 1024, H_ = 16, HD_ = 64;
constexpr float SCALE_ = 0.125f;   // HD^-0.5
constexpr float EPS_ = 1e-8f;

// ---------------------------------------------------------------- helpers
__device__ __forceinline__ void gload_lds16(const void* g, void* l) {
    __builtin_amdgcn_global_load_lds(
        (const __attribute__((address_space(1))) void*)g,
        (__attribute__((address_space(3))) void*)l, 16, 0, 0);
}

// ---------------------------------------------------------------- f32 -> bf16
__global__ __launch_bounds__(256) void cvt_kernel(const float* __restrict__ in,
                                                  bf16* __restrict__ out, int n4) {
    int i = blockIdx.x * 256 + threadIdx.x;
    if (i >= n4) return;
    float4v v = ((const float4v*)in)[i];
    bf16x4 o;
    o[0] = (bf16)v[0]; o[1] = (bf16)v[1]; o[2] = (bf16)v[2]; o[3] = (bf16)v[3];
    ((bf16x4*)out)[i] = o;
}

// ---------------------------------------------------------------- lp = mask + ln(clip(prior))
__global__ __launch_bounds__(256) void lp_kernel(const float* __restrict__ mask,
                                                 const float* __restrict__ prior,
                                                 float* __restrict__ lp, int n4) {
    int i = blockIdx.x * 256 + threadIdx.x;
    if (i >= n4) return;
    float4v m = ((const float4v*)mask)[i];
    float4v p = ((const float4v*)prior)[i];
    float4v o;
#pragma unroll
    for (int j = 0; j < 4; ++j) o[j] = m[j] + __logf(fmaxf(p[j], EPS_));
    ((float4v*)lp)[i] = o;
}

// ---------------------------------------------------------------- GEMM C = A(MxK) * B(NxK)^T
template<int OUTF32, int BIASED>
__global__ __launch_bounds__(256) void gemm_bt(const bf16* __restrict__ A,
                                               const bf16* __restrict__ B,
                                               void* __restrict__ Cp,
                                               const float* __restrict__ bias,
                                               int M, int N, int K) {
    __shared__ bf16 As[128 * 64];
    __shared__ bf16 Bs[128 * 64];
    const int lane = threadIdx.x & 63, wid = threadIdx.x >> 6;
    const int colL = lane & 15, grp = lane >> 4;
    const int bm = blockIdx.y * 128, bn = blockIdx.x * 128;
    const int wr = wid >> 1, wc = wid & 1;

    floatx4 acc[4][4];
#pragma unroll
    for (int m = 0; m < 4; ++m)
#pragma unroll
        for (int n = 0; n < 4; ++n) acc[m][n] = (floatx4){0.f, 0.f, 0.f, 0.f};

    for (int k0 = 0; k0 < K; k0 += 64) {
#pragma unroll
        for (int i = 0; i < 4; ++i) {
            int c = wid * 256 + i * 64 + lane;
            int row = c >> 3, sub = c & 7;
            gload_lds16(A + (size_t)(bm + row) * K + k0 + sub * 8,
                        &As[(wid * 256 + i * 64) * 8]);
            gload_lds16(B + (size_t)(bn + row) * K + k0 + sub * 8,
                        &Bs[(wid * 256 + i * 64) * 8]);
        }
        __syncthreads();
#pragma unroll
        for (int ks = 0; ks < 2; ++ks) {
            bf16x8 af[4], bfr[4];
#pragma unroll
            for (int m = 0; m < 4; ++m)
                af[m] = *(const bf16x8*)(&As[(wr * 64 + m * 16 + colL) * 64 + ks * 32 + grp * 8]);
#pragma unroll
            for (int n = 0; n < 4; ++n)
                bfr[n] = *(const bf16x8*)(&Bs[(wc * 64 + n * 16 + colL) * 64 + ks * 32 + grp * 8]);
#pragma unroll
            for (int m = 0; m < 4; ++m)
#pragma unroll
                for (int n = 0; n < 4; ++n)
                    acc[m][n] = MFMA16(af[m], bfr[n], acc[m][n]);
        }
        __syncthreads();
    }

#pragma unroll
    for (int m = 0; m < 4; ++m)
#pragma unroll
        for (int n = 0; n < 4; ++n)
#pragma unroll
            for (int r = 0; r < 4; ++r) {
                int row = bm + wr * 64 + m * 16 + grp * 4 + r;
                int col = bn + wc * 64 + n * 16 + colL;
                float v = acc[m][n][r];
                if (BIASED) v += bias[col];
                if (OUTF32) ((float*)Cp)[(size_t)row * N + col] = v;
                else        ((bf16*)Cp)[(size_t)row * N + col] = (bf16)v;
            }
}

// ---------------------------------------------------------------- RoPE (+scale), (B,S,DIM-slice) -> (B,H,S,HD)
__global__ __launch_bounds__(256) void rope_kernel(const bf16* __restrict__ in,
                                                   const float* __restrict__ fr,
                                                   bf16* __restrict__ out,
                                                   int in_ld, float scale) {
    int tid = blockIdx.x * 256 + threadIdx.x;
    int j = tid & 7, h = (tid >> 3) & 15, s = (tid >> 7) & 2047, b = tid >> 18;
    bf16x8 x = *(const bf16x8*)(in + (size_t)(b * 2048 + s) * in_ld + h * 64 + j * 8);
    const float* f = fr + (size_t)(b * 2048 + s) * 64 + j * 4;
    bf16x8 o;
#pragma unroll
    for (int i = 0; i < 4; ++i) {
        float c = f[i], sn = f[32 + i];
        float x0 = (float)x[2 * i], x1 = (float)x[2 * i + 1];
        o[2 * i]     = (bf16)((x0 * c - x1 * sn) * scale);
        o[2 * i + 1] = (bf16)((x0 * sn + x1 * c) * scale);
    }
    *(bf16x8*)(out + ((size_t)(b * 16 + h) * 2048 + s) * 64 + j * 8) = o;
}

// ---------------------------------------------------------------- V transpose: KVp(B,S,2048) v-part -> Vt(B,H,HD,S)
__global__ __launch_bounds__(256) void vtrans_kernel(const bf16* __restrict__ KVp,
                                                     bf16* __restrict__ Vt) {
    int bid = blockIdx.x;
    int sb = bid & 31, h = (bid >> 5) & 15, b = bid >> 9;
    __shared__ bf16 tile[64][66];
    int tid = threadIdx.x;
#pragma unroll
    for (int i = 0; i < 2; ++i) {
        int c = tid + i * 256;
        int row = c >> 3, sub = c & 7;
        bf16x8 x = *(const bf16x8*)(KVp + (size_t)(b * 2048 + sb * 64 + row) * 2048
                                    + 1024 + h * 64 + sub * 8);
#pragma unroll
        for (int k = 0; k < 8; ++k) tile[row][sub * 8 + k] = x[k];
    }
    __syncthreads();
#pragma unroll
    for (int i = 0; i < 2; ++i) {
        int c = tid + i * 256;
        int drow = c >> 3, sub = c & 7;
        bf16x8 o;
#pragma unroll
        for (int k = 0; k < 8; ++k) o[k] = tile[sub * 8 + k][drow];
        *(bf16x8*)(Vt + ((size_t)(b * 16 + h) * 64 + drow) * 2048 + sb * 64 + sub * 8) = o;
    }
}

// ---------------------------------------------------------------- fused attention, two-phase, shift-free
// R7 structure (measured best): Block = (b,h,64 q rows), 4 waves x 16 q rows.
// K, V, f32 lp-tile all LDS-staged via coalesced global_load_lds (dbuf,
// inverse-swizzled source), one barrier per tile. Phase 1: U + O. Phase 2:
// recompute logits, FS bounce, 256B-contiguous stores. XCD-swizzled grid.
// Added this round: T5 s_setprio around MFMA clusters (blocks independent).
__global__ __launch_bounds__(256) void attn_fused(const bf16* __restrict__ Qr,
                                                  const bf16* __restrict__ Kr,
                                                  const bf16* __restrict__ Vt,
                                                  const float* __restrict__ lp,
                                                  float* __restrict__ attn_out,
                                                  bf16* __restrict__ O) {
    __shared__ bf16 KB[2][4096];
    __shared__ float LP[2][4096];       // 64 rows x 64 f32, dbuf
    union ShU {
        struct { bf16 VB[2][4096]; bf16 P[4][1024]; } p1;   // phase 1
        float FS[4][1088];                                   // phase 2: 16 x 68 per wave
    };
    __shared__ ShU Ush;

    const int tid = threadIdx.x;
    const int lane = tid & 63, wv = tid >> 6;
    const int colL = lane & 15, grp = lane >> 4;
    // XCD swizzle: all 16 heads of a (b,qb) pair on one XCD
    const int n = blockIdx.x;
    const int x = n & 7, j = n >> 3;
    const int h = j & 15;
    const int pp = (j >> 4) * 8 + x;
    const int b = pp >> 5, qb = pp & 31;
    const int bh = b * H_ + h;
    const int q0 = qb * 64 + wv * 16;
    const int rowL = wv * 16 + colL;        // block-level q-row of this lane

    const bf16* Qbase = Qr + ((size_t)bh * S_ + q0) * HD_;
    const bf16* Kbase = Kr + (size_t)bh * S_ * HD_;
    const bf16* Vbase = Vt + (size_t)bh * HD_ * S_;
    const float* LPbase = lp + ((size_t)b * S_ + qb * 64) * S_;

    bf16x8 qf0 = *(const bf16x8*)(Qbase + (size_t)colL * HD_ + grp * 8);
    bf16x8 qf1 = *(const bf16x8*)(Qbase + (size_t)colL * HD_ + 32 + grp * 8);

    bf16* P = Ush.p1.P[wv];
    const int swz = (colL & 7) << 3;
    const int c7 = colL & 7;

    auto stageK = [&](int buf, int k0) {
#pragma unroll
        for (int i = 0; i < 2; ++i) {
            int c = i * 256 + tid;
            int row = c >> 3, sub = c & 7;
            gload_lds16(Kbase + (size_t)(k0 + row) * HD_ + ((sub ^ (row & 7)) << 3),
                        &KB[buf][(c & ~63) << 3]);
        }
    };
    auto stageV = [&](int buf, int k0) {
#pragma unroll
        for (int i = 0; i < 2; ++i) {
            int c = i * 256 + tid;
            int row = c >> 3, sub = c & 7;
            gload_lds16(Vbase + (size_t)row * S_ + k0 + ((sub ^ (row & 7)) << 3),
                        &Ush.p1.VB[buf][(c & ~63) << 3]);
        }
    };
    // lp tile: 64 rows x 64 f32 = 1024 x 16B chunks; row = c>>4, col16 = c&15
    auto stageLP = [&](int buf, int k0) {
#pragma unroll
        for (int i = 0; i < 4; ++i) {
            int c = i * 256 + tid;
            int row = c >> 4, col16 = c & 15;
            gload_lds16(LPbase + (size_t)row * S_ + k0 + ((col16 ^ (row & 7)) << 2),
                        &LP[buf][(c & ~63) << 2]);
        }
    };
    // lane's lp read address (word units) for sub-tile ct
    auto lpAddr = [&](int ct) {
        return rowL * 64 + (((ct * 4 + grp) ^ (rowL & 7)) << 2);
    };

    float ua = 0.f;
    floatx4 oT[4];
#pragma unroll
    for (int dt = 0; dt < 4; ++dt) oT[dt] = (floatx4){0.f, 0.f, 0.f, 0.f};

    // ---------------- phase 1 prologue
    stageK(0, 0);
    stageV(0, 0);
    stageLP(0, 0);
    __syncthreads();

    // ---------------- phase 1: U + O accumulation
    for (int kt = 0; kt < 32; ++kt) {
        const int k0 = kt * 64;
        const int cur = kt & 1;
        if (kt < 31) {
            stageK(cur ^ 1, k0 + 64);
            stageV(cur ^ 1, k0 + 64);
            stageLP(cur ^ 1, k0 + 64);
        }

        // QK^T from LDS
        floatx4 s[4];
        __builtin_amdgcn_s_setprio(1);
#pragma unroll
        for (int ct = 0; ct < 4; ++ct) {
            const int r8 = (ct * 16 + colL) * 8;
            bf16x8 a0 = *(const bf16x8*)&KB[cur][(r8 + (grp ^ c7)) * 8];
            bf16x8 a1 = *(const bf16x8*)&KB[cur][(r8 + (grp ^ 4 ^ c7)) * 8];
            floatx4 acc = (floatx4){0.f, 0.f, 0.f, 0.f};
            acc = MFMA16(a0, qf0, acc);
            acc = MFMA16(a1, qf1, acc);
            s[ct] = acc;
        }
        __builtin_amdgcn_s_setprio(0);
        // t = exp(s + lp)
#pragma unroll
        for (int ct = 0; ct < 4; ++ct) {
            float4v lv = *(const float4v*)&LP[cur][lpAddr(ct)];
            bf16x4 pw;
#pragma unroll
            for (int r = 0; r < 4; ++r) {
                float tv = __expf(s[ct][r] + lv[r]);
                ua += tv;
                pw[r] = (bf16)tv;
            }
            *(bf16x4*)&P[(colL * 64 + ct * 16 + grp * 4) ^ swz] = pw;
        }
        // PV from LDS V
        __builtin_amdgcn_s_setprio(1);
#pragma unroll
        for (int ks = 0; ks < 2; ++ks) {
            bf16x8 pb = *(const bf16x8*)&P[(colL * 64 + ks * 32 + grp * 8) ^ swz];
#pragma unroll
            for (int dt = 0; dt < 4; ++dt) {
                const int r8 = (dt * 16 + colL) * 8;
                bf16x8 vf = *(const bf16x8*)&Ush.p1.VB[cur][(r8 + ((ks * 4 + grp) ^ c7)) * 8];
                oT[dt] = MFMA16(vf, pb, oT[dt]);
            }
        }
        __builtin_amdgcn_s_setprio(0);
        __syncthreads();
    }

    // ---------------- U reduce + O write
    ua += __shfl_xor(ua, 16, 64);
    ua += __shfl_xor(ua, 32, 64);
    const float iu = 1.0f / ua;
#pragma unroll
    for (int dt = 0; dt < 4; ++dt) {
        bf16x4 ow;
#pragma unroll
        for (int r = 0; r < 4; ++r) ow[r] = (bf16)(oT[dt][r] * iu);
        *(bf16x4*)(O + ((size_t)b * S_ + q0 + colL) * DIM_ + h * HD_ + dt * 16 + grp * 4) = ow;
    }

    // ---------------- phase 2 prologue (FS aliases V/P space — safe after barrier)
    __syncthreads();
    stageK(0, 0);
    stageLP(0, 0);
    __syncthreads();

    // ---------------- phase 2: recompute, write attn = exp(s+lp)*invU, 256B stores
    const float* Aout = attn_out + (size_t)bh * S_ * S_;
    for (int kt = 0; kt < 32; ++kt) {
        const int k0 = kt * 64;
        const int cur = kt & 1;
        if (kt < 31) {
            stageK(cur ^ 1, k0 + 64);
            stageLP(cur ^ 1, k0 + 64);
        }

        floatx4 s[4];
        __builtin_amdgcn_s_setprio(1);
#pragma unroll
        for (int ct = 0; ct < 4; ++ct) {
            const int r8 = (ct * 16 + colL) * 8;
            bf16x8 a0 = *(const bf16x8*)&KB[cur][(r8 + (grp ^ c7)) * 8];
            bf16x8 a1 = *(const bf16x8*)&KB[cur][(r8 + (grp ^ 4 ^ c7)) * 8];
            floatx4 acc = (floatx4){0.f, 0.f, 0.f, 0.f};
            acc = MFMA16(a0, qf0, acc);
            acc = MFMA16(a1, qf1, acc);
            s[ct] = acc;
        }
        __builtin_amdgcn_s_setprio(0);
        // stage f32 tile into wave-private LDS (row = q-in-wave, col = k-in-tile)
#pragma unroll
        for (int ct = 0; ct < 4; ++ct) {
            float4v lv = *(const float4v*)&LP[cur][lpAddr(ct)];
            float4v o;
#pragma unroll
            for (int r = 0; r < 4; ++r)
                o[r] = __expf(s[ct][r] + lv[r]) * iu;
            *(float4v*)&Ush.FS[wv][colL * 68 + ct * 16 + grp * 4] = o;
        }
        // transposed read-out: 4 rows x 256B contiguous per instruction
#pragma unroll
        for (int it = 0; it < 4; ++it) {
            const int row = it * 4 + grp;
            float4v v = *(const float4v*)&Ush.FS[wv][row * 68 + colL * 4];
            *(float4v*)(Aout + (size_t)(q0 + row) * S_ + k0 + colL * 4) = v;
        }
        __syncthreads();
    }
}

// ---------------------------------------------------------------- launch
extern "C" void kernel_launch(void* const* d_in, const int* in_sizes, int n_in,
                              void* d_out, int out_size, void* d_ws, size_t ws_size,
                              hipStream_t stream) {
    const float* q_x   = (const float*)d_in[0];
    const float* kv_x  = (const float*)d_in[1];
    const float* q_fr  = (const float*)d_in[2];
    const float* k_fr  = (const float*)d_in[3];
    const float* maskp = (const float*)d_in[4];
    const float* prior = (const float*)d_in[5];
    const float* Wq    = (const float*)d_in[6];
    const float* Wkv   = (const float*)d_in[7];
    const float* Wproj = (const float*)d_in[8];
    const float* bproj = (const float*)d_in[9];

    float* out_x    = (float*)d_out;                       // (B,S,DIM)
    float* out_attn = out_x + (size_t)B_ * S_ * DIM_;      // (B,H,S,S)

    char* w = (char*)d_ws;
    bf16* qx_b  = (bf16*)(w + (size_t)0);          //  8 MiB
    bf16* kvx_b = (bf16*)(w + ((size_t)8  << 20)); //  8 MiB
    bf16* wq_b  = (bf16*)(w + ((size_t)16 << 20)); //  2 MiB
    bf16* wkv_b = (bf16*)(w + ((size_t)18 << 20)); //  4 MiB
    bf16* wpj_b = (bf16*)(w + ((size_t)22 << 20)); //  2 MiB
    bf16* qp    = (bf16*)(w + ((size_t)24 << 20)); //  8 MiB  (B,S,DIM)
    bf16* kvp   = (bf16*)(w + ((size_t)32 << 20)); // 16 MiB  (B,S,2*DIM)
    bf16* qr    = (bf16*)(w + ((size_t)48 << 20)); //  8 MiB  (B,H,S,HD)
    bf16* kr    = (bf16*)(w + ((size_t)56 << 20)); //  8 MiB
    bf16* vt    = (bf16*)(w + ((size_t)64 << 20)); //  8 MiB  (B,H,HD,S)
    bf16* ob    = (bf16*)(w + ((size_t)72 << 20)); //  8 MiB  (B,S,DIM)
    float* lpb  = (float*)(w + ((size_t)96 << 20)); // 32 MiB  (B,S,S) f32

    // f32 -> bf16 conversions + lp precompute
    cvt_kernel<<<4096, 256, 0, stream>>>(q_x,   qx_b,  1048576);
    cvt_kernel<<<4096, 256, 0, stream>>>(kv_x,  kvx_b, 1048576);
    cvt_kernel<<<1024, 256, 0, stream>>>(Wq,    wq_b,   262144);
    cvt_kernel<<<2048, 256, 0, stream>>>(Wkv,   wkv_b,  524288);
    cvt_kernel<<<1024, 256, 0, stream>>>(Wproj, wpj_b,  262144);
    lp_kernel<<<8192, 256, 0, stream>>>(maskp, prior, lpb, 2097152);

    // projections
    gemm_bt<0, 0><<<dim3(8, 32),  256, 0, stream>>>(qx_b,  wq_b,  qp,  nullptr, 4096, 1024, 1024);
    gemm_bt<0, 0><<<dim3(16, 32), 256, 0, stream>>>(kvx_b, wkv_b, kvp, nullptr, 4096, 2048, 1024);

    // RoPE + layout
    rope_kernel<<<2048, 256, 0, stream>>>(qp,  q_fr, qr, 1024, SCALE_);
    rope_kernel<<<2048, 256, 0, stream>>>(kvp, k_fr, kr, 2048, 1.0f);
    vtrans_kernel<<<1024, 256, 0, stream>>>(kvp, vt);

    // fused attention: O + attn in one kernel (XCD-swizzled grid)
    attn_fused<<<1024, 256, 0, stream>>>(qr, kr, vt, lpb, out_attn, ob);

    // output projection
    gemm_bt<1, 1><<<dim3(8, 32), 256, 0, stream>>>(ob, wpj_b, out_x, bproj, 4096, 1024, 1024);
}

// Round 13
// 372.888 us; speedup vs baseline: 1.2992x; 1.0979x over previous
//
#include <hip/hip_runtime.h>
#include <hip/hip_bf16.h>

typedef __bf16 bf16;
typedef __bf16 bf16x4 __attribute__((ext_vector_type(4)));
typedef __bf16 bf16x8 __attribute__((ext_vector_type(8)));
typedef float floatx4 __attribute__((ext_vector_type(4)));
typedef float float4v __attribute__((ext_vector_type(4)));

#define MFMA16(a, b, c) __builtin_amdgcn_mfma_f32_16x16x32_bf16(a, b, c, 0, 0, 0)

constexpr int B_ = 2, S_ = 2048, DIM_ = 1024, H_ = 16, HD_ = 64;
constexpr float SCALE_ = 0.125f;   // HD^-0.5
constexpr float EPS_ = 1e-8f;

// ---------------------------------------------------------------- helpers
__device__ __forceinline__ void gload_lds16(const void* g, void* l) {
    __builtin_amdgcn_global_load_lds(
        (const __attribute__((address_space(1))) void*)g,
        (__attribute__((address_space(3))) void*)l, 16, 0, 0);
}

// ---------------------------------------------------------------- f32 -> bf16
__global__ __launch_bounds__(256) void cvt_kernel(const float* __restrict__ in,
                                                  bf16* __restrict__ out, int n4) {
    int i = blockIdx.x * 256 + threadIdx.x;
    if (i >= n4) return;
    float4v v = ((const float4v*)in)[i];
    bf16x4 o;
    o[0] = (bf16)v[0]; o[1] = (bf16)v[1]; o[2] = (bf16)v[2]; o[3] = (bf16)v[3];
    ((bf16x4*)out)[i] = o;
}

// ---------------------------------------------------------------- lp = mask + ln(clip(prior))
__global__ __launch_bounds__(256) void lp_kernel(const float* __restrict__ mask,
                                                 const float* __restrict__ prior,
                                                 float* __restrict__ lp, int n4) {
    int i = blockIdx.x * 256 + threadIdx.x;
    if (i >= n4) return;
    float4v m = ((const float4v*)mask)[i];
    float4v p = ((const float4v*)prior)[i];
    float4v o;
#pragma unroll
    for (int j = 0; j < 4; ++j) o[j] = m[j] + __logf(fmaxf(p[j], EPS_));
    ((float4v*)lp)[i] = o;
}

// ---------------------------------------------------------------- GEMM C = A(MxK) * B(NxK)^T
template<int OUTF32, int BIASED>
__global__ __launch_bounds__(256) void gemm_bt(const bf16* __restrict__ A,
                                               const bf16* __restrict__ B,
                                               void* __restrict__ Cp,
                                               const float* __restrict__ bias,
                                               int M, int N, int K) {
    __shared__ bf16 As[128 * 64];
    __shared__ bf16 Bs[128 * 64];
    const int lane = threadIdx.x & 63, wid = threadIdx.x >> 6;
    const int colL = lane & 15, grp = lane >> 4;
    const int bm = blockIdx.y * 128, bn = blockIdx.x * 128;
    const int wr = wid >> 1, wc = wid & 1;

    floatx4 acc[4][4];
#pragma unroll
    for (int m = 0; m < 4; ++m)
#pragma unroll
        for (int n = 0; n < 4; ++n) acc[m][n] = (floatx4){0.f, 0.f, 0.f, 0.f};

    for (int k0 = 0; k0 < K; k0 += 64) {
#pragma unroll
        for (int i = 0; i < 4; ++i) {
            int c = wid * 256 + i * 64 + lane;
            int row = c >> 3, sub = c & 7;
            gload_lds16(A + (size_t)(bm + row) * K + k0 + sub * 8,
                        &As[(wid * 256 + i * 64) * 8]);
            gload_lds16(B + (size_t)(bn + row) * K + k0 + sub * 8,
                        &Bs[(wid * 256 + i * 64) * 8]);
        }
        __syncthreads();
#pragma unroll
        for (int ks = 0; ks < 2; ++ks) {
            bf16x8 af[4], bfr[4];
#pragma unroll
            for (int m = 0; m < 4; ++m)
                af[m] = *(const bf16x8*)(&As[(wr * 64 + m * 16 + colL) * 64 + ks * 32 + grp * 8]);
#pragma unroll
            for (int n = 0; n < 4; ++n)
                bfr[n] = *(const bf16x8*)(&Bs[(wc * 64 + n * 16 + colL) * 64 + ks * 32 + grp * 8]);
#pragma unroll
            for (int m = 0; m < 4; ++m)
#pragma unroll
                for (int n = 0; n < 4; ++n)
                    acc[m][n] = MFMA16(af[m], bfr[n], acc[m][n]);
        }
        __syncthreads();
    }

#pragma unroll
    for (int m = 0; m < 4; ++m)
#pragma unroll
        for (int n = 0; n < 4; ++n)
#pragma unroll
            for (int r = 0; r < 4; ++r) {
                int row = bm + wr * 64 + m * 16 + grp * 4 + r;
                int col = bn + wc * 64 + n * 16 + colL;
                float v = acc[m][n][r];
                if (BIASED) v += bias[col];
                if (OUTF32) ((float*)Cp)[(size_t)row * N + col] = v;
                else        ((bf16*)Cp)[(size_t)row * N + col] = (bf16)v;
            }
}

// ---------------------------------------------------------------- RoPE (+scale), (B,S,DIM-slice) -> (B,H,S,HD)
__global__ __launch_bounds__(256) void rope_kernel(const bf16* __restrict__ in,
                                                   const float* __restrict__ fr,
                                                   bf16* __restrict__ out,
                                                   int in_ld, float scale) {
    int tid = blockIdx.x * 256 + threadIdx.x;
    int j = tid & 7, h = (tid >> 3) & 15, s = (tid >> 7) & 2047, b = tid >> 18;
    bf16x8 x = *(const bf16x8*)(in + (size_t)(b * 2048 + s) * in_ld + h * 64 + j * 8);
    const float* f = fr + (size_t)(b * 2048 + s) * 64 + j * 4;
    bf16x8 o;
#pragma unroll
    for (int i = 0; i < 4; ++i) {
        float c = f[i], sn = f[32 + i];
        float x0 = (float)x[2 * i], x1 = (float)x[2 * i + 1];
        o[2 * i]     = (bf16)((x0 * c - x1 * sn) * scale);
        o[2 * i + 1] = (bf16)((x0 * sn + x1 * c) * scale);
    }
    *(bf16x8*)(out + ((size_t)(b * 16 + h) * 2048 + s) * 64 + j * 8) = o;
}

// ---------------------------------------------------------------- V transpose: KVp(B,S,2048) v-part -> Vt(B,H,HD,S)
__global__ __launch_bounds__(256) void vtrans_kernel(const bf16* __restrict__ KVp,
                                                     bf16* __restrict__ Vt) {
    int bid = blockIdx.x;
    int sb = bid & 31, h = (bid >> 5) & 15, b = bid >> 9;
    __shared__ bf16 tile[64][66];
    int tid = threadIdx.x;
#pragma unroll
    for (int i = 0; i < 2; ++i) {
        int c = tid + i * 256;
        int row = c >> 3, sub = c & 7;
        bf16x8 x = *(const bf16x8*)(KVp + (size_t)(b * 2048 + sb * 64 + row) * 2048
                                    + 1024 + h * 64 + sub * 8);
#pragma unroll
        for (int k = 0; k < 8; ++k) tile[row][sub * 8 + k] = x[k];
    }
    __syncthreads();
#pragma unroll
    for (int i = 0; i < 2; ++i) {
        int c = tid + i * 256;
        int drow = c >> 3, sub = c & 7;
        bf16x8 o;
#pragma unroll
        for (int k = 0; k < 8; ++k) o[k] = tile[sub * 8 + k][drow];
        *(bf16x8*)(Vt + ((size_t)(b * 16 + h) * 64 + drow) * 2048 + sb * 64 + sub * 8) = o;
    }
}

// ---------------------------------------------------------------- fused attention, two-phase, shift-free
// R12 structure (measured best: 409 us total) + NON-TEMPORAL attn stores.
// Block = (b,h,64 q rows), 4 waves x 16 q rows. K, V, f32 lp-tile all LDS-staged
// via coalesced global_load_lds (dbuf, inverse-swizzled source), one barrier per
// tile. Phase 1: U + O. Phase 2: recompute logits, FS bounce, 256B-contiguous
// nt-stores (attn is never re-read -> bypass L2, keep K/LP/V hot). T5 setprio
// around MFMA clusters. XCD-swizzled grid.
__global__ __launch_bounds__(256) void attn_fused(const bf16* __restrict__ Qr,
                                                  const bf16* __restrict__ Kr,
                                                  const bf16* __restrict__ Vt,
                                                  const float* __restrict__ lp,
                                                  float* __restrict__ attn_out,
                                                  bf16* __restrict__ O) {
    __shared__ bf16 KB[2][4096];
    __shared__ float LP[2][4096];       // 64 rows x 64 f32, dbuf
    union ShU {
        struct { bf16 VB[2][4096]; bf16 P[4][1024]; } p1;   // phase 1
        float FS[4][1088];                                   // phase 2: 16 x 68 per wave
    };
    __shared__ ShU Ush;

    const int tid = threadIdx.x;
    const int lane = tid & 63, wv = tid >> 6;
    const int colL = lane & 15, grp = lane >> 4;
    // XCD swizzle: all 16 heads of a (b,qb) pair on one XCD
    const int n = blockIdx.x;
    const int x = n & 7, j = n >> 3;
    const int h = j & 15;
    const int pp = (j >> 4) * 8 + x;
    const int b = pp >> 5, qb = pp & 31;
    const int bh = b * H_ + h;
    const int q0 = qb * 64 + wv * 16;
    const int rowL = wv * 16 + colL;        // block-level q-row of this lane

    const bf16* Qbase = Qr + ((size_t)bh * S_ + q0) * HD_;
    const bf16* Kbase = Kr + (size_t)bh * S_ * HD_;
    const bf16* Vbase = Vt + (size_t)bh * HD_ * S_;
    const float* LPbase = lp + ((size_t)b * S_ + qb * 64) * S_;

    bf16x8 qf0 = *(const bf16x8*)(Qbase + (size_t)colL * HD_ + grp * 8);
    bf16x8 qf1 = *(const bf16x8*)(Qbase + (size_t)colL * HD_ + 32 + grp * 8);

    bf16* P = Ush.p1.P[wv];
    const int swz = (colL & 7) << 3;
    const int c7 = colL & 7;

    auto stageK = [&](int buf, int k0) {
#pragma unroll
        for (int i = 0; i < 2; ++i) {
            int c = i * 256 + tid;
            int row = c >> 3, sub = c & 7;
            gload_lds16(Kbase + (size_t)(k0 + row) * HD_ + ((sub ^ (row & 7)) << 3),
                        &KB[buf][(c & ~63) << 3]);
        }
    };
    auto stageV = [&](int buf, int k0) {
#pragma unroll
        for (int i = 0; i < 2; ++i) {
            int c = i * 256 + tid;
            int row = c >> 3, sub = c & 7;
            gload_lds16(Vbase + (size_t)row * S_ + k0 + ((sub ^ (row & 7)) << 3),
                        &Ush.p1.VB[buf][(c & ~63) << 3]);
        }
    };
    // lp tile: 64 rows x 64 f32 = 1024 x 16B chunks; row = c>>4, col16 = c&15
    auto stageLP = [&](int buf, int k0) {
#pragma unroll
        for (int i = 0; i < 4; ++i) {
            int c = i * 256 + tid;
            int row = c >> 4, col16 = c & 15;
            gload_lds16(LPbase + (size_t)row * S_ + k0 + ((col16 ^ (row & 7)) << 2),
                        &LP[buf][(c & ~63) << 2]);
        }
    };
    // lane's lp read address (word units) for sub-tile ct
    auto lpAddr = [&](int ct) {
        return rowL * 64 + (((ct * 4 + grp) ^ (rowL & 7)) << 2);
    };

    float ua = 0.f;
    floatx4 oT[4];
#pragma unroll
    for (int dt = 0; dt < 4; ++dt) oT[dt] = (floatx4){0.f, 0.f, 0.f, 0.f};

    // ---------------- phase 1 prologue
    stageK(0, 0);
    stageV(0, 0);
    stageLP(0, 0);
    __syncthreads();

    // ---------------- phase 1: U + O accumulation
    for (int kt = 0; kt < 32; ++kt) {
        const int k0 = kt * 64;
        const int cur = kt & 1;
        if (kt < 31) {
            stageK(cur ^ 1, k0 + 64);
            stageV(cur ^ 1, k0 + 64);
            stageLP(cur ^ 1, k0 + 64);
        }

        // QK^T from LDS
        floatx4 s[4];
        __builtin_amdgcn_s_setprio(1);
#pragma unroll
        for (int ct = 0; ct < 4; ++ct) {
            const int r8 = (ct * 16 + colL) * 8;
            bf16x8 a0 = *(const bf16x8*)&KB[cur][(r8 + (grp ^ c7)) * 8];
            bf16x8 a1 = *(const bf16x8*)&KB[cur][(r8 + (grp ^ 4 ^ c7)) * 8];
            floatx4 acc = (floatx4){0.f, 0.f, 0.f, 0.f};
            acc = MFMA16(a0, qf0, acc);
            acc = MFMA16(a1, qf1, acc);
            s[ct] = acc;
        }
        __builtin_amdgcn_s_setprio(0);
        // t = exp(s + lp)
#pragma unroll
        for (int ct = 0; ct < 4; ++ct) {
            float4v lv = *(const float4v*)&LP[cur][lpAddr(ct)];
            bf16x4 pw;
#pragma unroll
            for (int r = 0; r < 4; ++r) {
                float tv = __expf(s[ct][r] + lv[r]);
                ua += tv;
                pw[r] = (bf16)tv;
            }
            *(bf16x4*)&P[(colL * 64 + ct * 16 + grp * 4) ^ swz] = pw;
        }
        // PV from LDS V
        __builtin_amdgcn_s_setprio(1);
#pragma unroll
        for (int ks = 0; ks < 2; ++ks) {
            bf16x8 pb = *(const bf16x8*)&P[(colL * 64 + ks * 32 + grp * 8) ^ swz];
#pragma unroll
            for (int dt = 0; dt < 4; ++dt) {
                const int r8 = (dt * 16 + colL) * 8;
                bf16x8 vf = *(const bf16x8*)&Ush.p1.VB[cur][(r8 + ((ks * 4 + grp) ^ c7)) * 8];
                oT[dt] = MFMA16(vf, pb, oT[dt]);
            }
        }
        __builtin_amdgcn_s_setprio(0);
        __syncthreads();
    }

    // ---------------- U reduce + O write
    ua += __shfl_xor(ua, 16, 64);
    ua += __shfl_xor(ua, 32, 64);
    const float iu = 1.0f / ua;
#pragma unroll
    for (int dt = 0; dt < 4; ++dt) {
        bf16x4 ow;
#pragma unroll
        for (int r = 0; r < 4; ++r) ow[r] = (bf16)(oT[dt][r] * iu);
        *(bf16x4*)(O + ((size_t)b * S_ + q0 + colL) * DIM_ + h * HD_ + dt * 16 + grp * 4) = ow;
    }

    // ---------------- phase 2 prologue (FS aliases V/P space — safe after barrier)
    __syncthreads();
    stageK(0, 0);
    stageLP(0, 0);
    __syncthreads();

    // ---------------- phase 2: recompute, nt-write attn = exp(s+lp)*invU
    const float* Aout = attn_out + (size_t)bh * S_ * S_;
    for (int kt = 0; kt < 32; ++kt) {
        const int k0 = kt * 64;
        const int cur = kt & 1;
        if (kt < 31) {
            stageK(cur ^ 1, k0 + 64);
            stageLP(cur ^ 1, k0 + 64);
        }

        floatx4 s[4];
        __builtin_amdgcn_s_setprio(1);
#pragma unroll
        for (int ct = 0; ct < 4; ++ct) {
            const int r8 = (ct * 16 + colL) * 8;
            bf16x8 a0 = *(const bf16x8*)&KB[cur][(r8 + (grp ^ c7)) * 8];
            bf16x8 a1 = *(const bf16x8*)&KB[cur][(r8 + (grp ^ 4 ^ c7)) * 8];
            floatx4 acc = (floatx4){0.f, 0.f, 0.f, 0.f};
            acc = MFMA16(a0, qf0, acc);
            acc = MFMA16(a1, qf1, acc);
            s[ct] = acc;
        }
        __builtin_amdgcn_s_setprio(0);
        // stage f32 tile into wave-private LDS (row = q-in-wave, col = k-in-tile)
#pragma unroll
        for (int ct = 0; ct < 4; ++ct) {
            float4v lv = *(const float4v*)&LP[cur][lpAddr(ct)];
            float4v o;
#pragma unroll
            for (int r = 0; r < 4; ++r)
                o[r] = __expf(s[ct][r] + lv[r]) * iu;
            *(float4v*)&Ush.FS[wv][colL * 68 + ct * 16 + grp * 4] = o;
        }
        // transposed read-out: 4 rows x 256B contiguous, NON-TEMPORAL stores
#pragma unroll
        for (int it = 0; it < 4; ++it) {
            const int row = it * 4 + grp;
            float4v v = *(const float4v*)&Ush.FS[wv][row * 68 + colL * 4];
            __builtin_nontemporal_store(v,
                (float4v*)(Aout + (size_t)(q0 + row) * S_ + k0 + colL * 4));
        }
        __syncthreads();
    }
}

// ---------------------------------------------------------------- launch
extern "C" void kernel_launch(void* const* d_in, const int* in_sizes, int n_in,
                              void* d_out, int out_size, void* d_ws, size_t ws_size,
                              hipStream_t stream) {
    const float* q_x   = (const float*)d_in[0];
    const float* kv_x  = (const float*)d_in[1];
    const float* q_fr  = (const float*)d_in[2];
    const float* k_fr  = (const float*)d_in[3];
    const float* maskp = (const float*)d_in[4];
    const float* prior = (const float*)d_in[5];
    const float* Wq    = (const float*)d_in[6];
    const float* Wkv   = (const float*)d_in[7];
    const float* Wproj = (const float*)d_in[8];
    const float* bproj = (const float*)d_in[9];

    float* out_x    = (float*)d_out;                       // (B,S,DIM)
    float* out_attn = out_x + (size_t)B_ * S_ * DIM_;      // (B,H,S,S)

    char* w = (char*)d_ws;
    bf16* qx_b  = (bf16*)(w + (size_t)0);          //  8 MiB
    bf16* kvx_b = (bf16*)(w + ((size_t)8  << 20)); //  8 MiB
    bf16* wq_b  = (bf16*)(w + ((size_t)16 << 20)); //  2 MiB
    bf16* wkv_b = (bf16*)(w + ((size_t)18 << 20)); //  4 MiB
    bf16* wpj_b = (bf16*)(w + ((size_t)22 << 20)); //  2 MiB
    bf16* qp    = (bf16*)(w + ((size_t)24 << 20)); //  8 MiB  (B,S,DIM)
    bf16* kvp   = (bf16*)(w + ((size_t)32 << 20)); // 16 MiB  (B,S,2*DIM)
    bf16* qr    = (bf16*)(w + ((size_t)48 << 20)); //  8 MiB  (B,H,S,HD)
    bf16* kr    = (bf16*)(w + ((size_t)56 << 20)); //  8 MiB
    bf16* vt    = (bf16*)(w + ((size_t)64 << 20)); //  8 MiB  (B,H,HD,S)
    bf16* ob    = (bf16*)(w + ((size_t)72 << 20)); //  8 MiB  (B,S,DIM)
    float* lpb  = (float*)(w + ((size_t)96 << 20)); // 32 MiB  (B,S,S) f32

    // f32 -> bf16 conversions + lp precompute
    cvt_kernel<<<4096, 256, 0, stream>>>(q_x,   qx_b,  1048576);
    cvt_kernel<<<4096, 256, 0, stream>>>(kv_x,  kvx_b, 1048576);
    cvt_kernel<<<1024, 256, 0, stream>>>(Wq,    wq_b,   262144);
    cvt_kernel<<<2048, 256, 0, stream>>>(Wkv,   wkv_b,  524288);
    cvt_kernel<<<1024, 256, 0, stream>>>(Wproj, wpj_b,  262144);
    lp_kernel<<<8192, 256, 0, stream>>>(maskp, prior, lpb, 2097152);

    // projections
    gemm_bt<0, 0><<<dim3(8, 32),  256, 0, stream>>>(qx_b,  wq_b,  qp,  nullptr, 4096, 1024, 1024);
    gemm_bt<0, 0><<<dim3(16, 32), 256, 0, stream>>>(kvx_b, wkv_b, kvp, nullptr, 4096, 2048, 1024);

    // RoPE + layout
    rope_kernel<<<2048, 256, 0, stream>>>(qp,  q_fr, qr, 1024, SCALE_);
    rope_kernel<<<2048, 256, 0, stream>>>(kvp, k_fr, kr, 2048, 1.0f);
    vtrans_kernel<<<1024, 256, 0, stream>>>(kvp, vt);

    // fused attention: O + attn in one kernel (XCD-swizzled grid)
    attn_fused<<<1024, 256, 0, stream>>>(qr, kr, vt, lpb, out_attn, ob);

    // output projection
    gemm_bt<1, 1><<<dim3(8, 32), 256, 0, stream>>>(ob, wpj_b, out_x, bproj, 4096, 1024, 1024);
}

// Round 14
// 368.303 us; speedup vs baseline: 1.3153x; 1.0124x over previous
//
#include <hip/hip_runtime.h>
#include <hip/hip_bf16.h>

typedef __bf16 bf16;
typedef __bf16 bf16x4 __attribute__((ext_vector_type(4)));
typedef __bf16 bf16x8 __attribute__((ext_vector_type(8)));
typedef float floatx4 __attribute__((ext_vector_type(4)));
typedef float float4v __attribute__((ext_vector_type(4)));

#define MFMA16(a, b, c) __builtin_amdgcn_mfma_f32_16x16x32_bf16(a, b, c, 0, 0, 0)

constexpr int B_ = 2, S_ = 2048, DIM_ = 1024, H_ = 16, HD_ = 64;
constexpr float SCALE_ = 0.125f;   // HD^-0.5
constexpr float EPS_ = 1e-8f;

// ---------------------------------------------------------------- helpers
__device__ __forceinline__ void gload_lds16(const void* g, void* l) {
    __builtin_amdgcn_global_load_lds(
        (const __attribute__((address_space(1))) void*)g,
        (__attribute__((address_space(3))) void*)l, 16, 0, 0);
}

// ---------------------------------------------------------------- prep: all f32->bf16 cvts + lp, one kernel
// blocks [0,4096) q_x | [4096,8192) kv_x | [8192,9216) Wq | [9216,11264) Wkv
// | [11264,12288) Wproj | [12288,20480) lp = mask + ln(clip(prior))
__global__ __launch_bounds__(256) void prep_kernel(const float* __restrict__ q_x,
                                                   const float* __restrict__ kv_x,
                                                   const float* __restrict__ Wq,
                                                   const float* __restrict__ Wkv,
                                                   const float* __restrict__ Wproj,
                                                   const float* __restrict__ mask,
                                                   const float* __restrict__ prior,
                                                   bf16* __restrict__ qx_b,
                                                   bf16* __restrict__ kvx_b,
                                                   bf16* __restrict__ wq_b,
                                                   bf16* __restrict__ wkv_b,
                                                   bf16* __restrict__ wpj_b,
                                                   float* __restrict__ lp) {
    const int blk = blockIdx.x, t = threadIdx.x;
    auto cvt = [&](const float* in, bf16* out, int base) {
        int i = base * 256 + t;
        float4v v = __builtin_nontemporal_load((const float4v*)in + i);
        bf16x4 o;
#pragma unroll
        for (int j = 0; j < 4; ++j) o[j] = (bf16)v[j];
        ((bf16x4*)out)[i] = o;           // normal store: re-read by GEMMs
    };
    if (blk < 4096)        cvt(q_x,   qx_b,  blk);
    else if (blk < 8192)   cvt(kv_x,  kvx_b, blk - 4096);
    else if (blk < 9216)   cvt(Wq,    wq_b,  blk - 8192);
    else if (blk < 11264)  cvt(Wkv,   wkv_b, blk - 9216);
    else if (blk < 12288)  cvt(Wproj, wpj_b, blk - 11264);
    else {
        int i = (blk - 12288) * 256 + t;
        float4v m = __builtin_nontemporal_load((const float4v*)mask + i);
        float4v p = __builtin_nontemporal_load((const float4v*)prior + i);
        float4v o;
#pragma unroll
        for (int j = 0; j < 4; ++j) o[j] = m[j] + __logf(fmaxf(p[j], EPS_));
        ((float4v*)lp)[i] = o;           // normal store: re-read 16x by attn
    }
}

// ---------------------------------------------------------------- GEMM C = A(MxK) * B(NxK)^T
template<int OUTF32, int BIASED>
__global__ __launch_bounds__(256) void gemm_bt(const bf16* __restrict__ A,
                                               const bf16* __restrict__ B,
                                               void* __restrict__ Cp,
                                               const float* __restrict__ bias,
                                               int M, int N, int K) {
    __shared__ bf16 As[128 * 64];
    __shared__ bf16 Bs[128 * 64];
    const int lane = threadIdx.x & 63, wid = threadIdx.x >> 6;
    const int colL = lane & 15, grp = lane >> 4;
    const int bm = blockIdx.y * 128, bn = blockIdx.x * 128;
    const int wr = wid >> 1, wc = wid & 1;

    floatx4 acc[4][4];
#pragma unroll
    for (int m = 0; m < 4; ++m)
#pragma unroll
        for (int n = 0; n < 4; ++n) acc[m][n] = (floatx4){0.f, 0.f, 0.f, 0.f};

    for (int k0 = 0; k0 < K; k0 += 64) {
#pragma unroll
        for (int i = 0; i < 4; ++i) {
            int c = wid * 256 + i * 64 + lane;
            int row = c >> 3, sub = c & 7;
            gload_lds16(A + (size_t)(bm + row) * K + k0 + sub * 8,
                        &As[(wid * 256 + i * 64) * 8]);
            gload_lds16(B + (size_t)(bn + row) * K + k0 + sub * 8,
                        &Bs[(wid * 256 + i * 64) * 8]);
        }
        __syncthreads();
#pragma unroll
        for (int ks = 0; ks < 2; ++ks) {
            bf16x8 af[4], bfr[4];
#pragma unroll
            for (int m = 0; m < 4; ++m)
                af[m] = *(const bf16x8*)(&As[(wr * 64 + m * 16 + colL) * 64 + ks * 32 + grp * 8]);
#pragma unroll
            for (int n = 0; n < 4; ++n)
                bfr[n] = *(const bf16x8*)(&Bs[(wc * 64 + n * 16 + colL) * 64 + ks * 32 + grp * 8]);
#pragma unroll
            for (int m = 0; m < 4; ++m)
#pragma unroll
                for (int n = 0; n < 4; ++n)
                    acc[m][n] = MFMA16(af[m], bfr[n], acc[m][n]);
        }
        __syncthreads();
    }

#pragma unroll
    for (int m = 0; m < 4; ++m)
#pragma unroll
        for (int n = 0; n < 4; ++n)
#pragma unroll
            for (int r = 0; r < 4; ++r) {
                int row = bm + wr * 64 + m * 16 + grp * 4 + r;
                int col = bn + wc * 64 + n * 16 + colL;
                float v = acc[m][n][r];
                if (BIASED) v += bias[col];
                if (OUTF32)
                    __builtin_nontemporal_store(v, (float*)Cp + (size_t)row * N + col);
                else
                    ((bf16*)Cp)[(size_t)row * N + col] = (bf16)v;
            }
}

// ---------------------------------------------------------------- rope (q,k) + vtrans, one kernel
// blocks [0,2048) rope-q | [2048,4096) rope-k | [4096,5120) vtrans
__global__ __launch_bounds__(256) void rope_vt_kernel(const bf16* __restrict__ qp,
                                                      const bf16* __restrict__ kvp,
                                                      const float* __restrict__ q_fr,
                                                      const float* __restrict__ k_fr,
                                                      bf16* __restrict__ qr,
                                                      bf16* __restrict__ kr,
                                                      bf16* __restrict__ vt) {
    __shared__ bf16 tile[64][66];
    const int blk = blockIdx.x;
    if (blk < 4096) {
        const bf16* in   = (blk < 2048) ? qp : kvp;
        const float* fr  = (blk < 2048) ? q_fr : k_fr;
        bf16* out        = (blk < 2048) ? qr : kr;
        const int in_ld  = (blk < 2048) ? 1024 : 2048;
        const float scale = (blk < 2048) ? SCALE_ : 1.0f;
        int tid = (blk & 2047) * 256 + threadIdx.x;
        int j = tid & 7, h = (tid >> 3) & 15, s = (tid >> 7) & 2047, b = tid >> 18;
        bf16x8 x = *(const bf16x8*)(in + (size_t)(b * 2048 + s) * in_ld + h * 64 + j * 8);
        const float* f = fr + (size_t)(b * 2048 + s) * 64 + j * 4;
        bf16x8 o;
#pragma unroll
        for (int i = 0; i < 4; ++i) {
            float c = f[i], sn = f[32 + i];
            float x0 = (float)x[2 * i], x1 = (float)x[2 * i + 1];
            o[2 * i]     = (bf16)((x0 * c - x1 * sn) * scale);
            o[2 * i + 1] = (bf16)((x0 * sn + x1 * c) * scale);
        }
        *(bf16x8*)(out + ((size_t)(b * 16 + h) * 2048 + s) * 64 + j * 8) = o;
    } else {
        const int bid = blk - 4096;
        const int sb = bid & 31, h = (bid >> 5) & 15, b = bid >> 9;
        const int tid = threadIdx.x;
#pragma unroll
        for (int i = 0; i < 2; ++i) {
            int c = tid + i * 256;
            int row = c >> 3, sub = c & 7;
            bf16x8 x = *(const bf16x8*)(kvp + (size_t)(b * 2048 + sb * 64 + row) * 2048
                                        + 1024 + h * 64 + sub * 8);
#pragma unroll
            for (int k = 0; k < 8; ++k) tile[row][sub * 8 + k] = x[k];
        }
        __syncthreads();
#pragma unroll
        for (int i = 0; i < 2; ++i) {
            int c = tid + i * 256;
            int drow = c >> 3, sub = c & 7;
            bf16x8 o;
#pragma unroll
            for (int k = 0; k < 8; ++k) o[k] = tile[sub * 8 + k][drow];
            *(bf16x8*)(vt + ((size_t)(b * 16 + h) * 64 + drow) * 2048 + sb * 64 + sub * 8) = o;
        }
    }
}

// ---------------------------------------------------------------- fused attention, two-phase, shift-free
// R13 structure (measured best: 373 us total). Block = (b,h,64 q rows), 4 waves
// x 16 q rows. K, V, f32 lp-tile all LDS-staged via coalesced global_load_lds
// (dbuf, inverse-swizzled source), one barrier per tile. Phase 1: U + O.
// Phase 2: recompute logits, FS bounce, 256B-contiguous NT stores. T5 setprio
// around MFMA clusters. XCD-swizzled grid.
__global__ __launch_bounds__(256) void attn_fused(const bf16* __restrict__ Qr,
                                                  const bf16* __restrict__ Kr,
                                                  const bf16* __restrict__ Vt,
                                                  const float* __restrict__ lp,
                                                  float* __restrict__ attn_out,
                                                  bf16* __restrict__ O) {
    __shared__ bf16 KB[2][4096];
    __shared__ float LP[2][4096];       // 64 rows x 64 f32, dbuf
    union ShU {
        struct { bf16 VB[2][4096]; bf16 P[4][1024]; } p1;   // phase 1
        float FS[4][1088];                                   // phase 2: 16 x 68 per wave
    };
    __shared__ ShU Ush;

    const int tid = threadIdx.x;
    const int lane = tid & 63, wv = tid >> 6;
    const int colL = lane & 15, grp = lane >> 4;
    // XCD swizzle: all 16 heads of a (b,qb) pair on one XCD
    const int n = blockIdx.x;
    const int x = n & 7, j = n >> 3;
    const int h = j & 15;
    const int pp = (j >> 4) * 8 + x;
    const int b = pp >> 5, qb = pp & 31;
    const int bh = b * H_ + h;
    const int q0 = qb * 64 + wv * 16;
    const int rowL = wv * 16 + colL;        // block-level q-row of this lane

    const bf16* Qbase = Qr + ((size_t)bh * S_ + q0) * HD_;
    const bf16* Kbase = Kr + (size_t)bh * S_ * HD_;
    const bf16* Vbase = Vt + (size_t)bh * HD_ * S_;
    const float* LPbase = lp + ((size_t)b * S_ + qb * 64) * S_;

    bf16x8 qf0 = *(const bf16x8*)(Qbase + (size_t)colL * HD_ + grp * 8);
    bf16x8 qf1 = *(const bf16x8*)(Qbase + (size_t)colL * HD_ + 32 + grp * 8);

    bf16* P = Ush.p1.P[wv];
    const int swz = (colL & 7) << 3;
    const int c7 = colL & 7;

    auto stageK = [&](int buf, int k0) {
#pragma unroll
        for (int i = 0; i < 2; ++i) {
            int c = i * 256 + tid;
            int row = c >> 3, sub = c & 7;
            gload_lds16(Kbase + (size_t)(k0 + row) * HD_ + ((sub ^ (row & 7)) << 3),
                        &KB[buf][(c & ~63) << 3]);
        }
    };
    auto stageV = [&](int buf, int k0) {
#pragma unroll
        for (int i = 0; i < 2; ++i) {
            int c = i * 256 + tid;
            int row = c >> 3, sub = c & 7;
            gload_lds16(Vbase + (size_t)row * S_ + k0 + ((sub ^ (row & 7)) << 3),
                        &Ush.p1.VB[buf][(c & ~63) << 3]);
        }
    };
    // lp tile: 64 rows x 64 f32 = 1024 x 16B chunks; row = c>>4, col16 = c&15
    auto stageLP = [&](int buf, int k0) {
#pragma unroll
        for (int i = 0; i < 4; ++i) {
            int c = i * 256 + tid;
            int row = c >> 4, col16 = c & 15;
            gload_lds16(LPbase + (size_t)row * S_ + k0 + ((col16 ^ (row & 7)) << 2),
                        &LP[buf][(c & ~63) << 2]);
        }
    };
    // lane's lp read address (word units) for sub-tile ct
    auto lpAddr = [&](int ct) {
        return rowL * 64 + (((ct * 4 + grp) ^ (rowL & 7)) << 2);
    };

    float ua = 0.f;
    floatx4 oT[4];
#pragma unroll
    for (int dt = 0; dt < 4; ++dt) oT[dt] = (floatx4){0.f, 0.f, 0.f, 0.f};

    // ---------------- phase 1 prologue
    stageK(0, 0);
    stageV(0, 0);
    stageLP(0, 0);
    __syncthreads();

    // ---------------- phase 1: U + O accumulation
    for (int kt = 0; kt < 32; ++kt) {
        const int k0 = kt * 64;
        const int cur = kt & 1;
        if (kt < 31) {
            stageK(cur ^ 1, k0 + 64);
            stageV(cur ^ 1, k0 + 64);
            stageLP(cur ^ 1, k0 + 64);
        }

        // QK^T from LDS
        floatx4 s[4];
        __builtin_amdgcn_s_setprio(1);
#pragma unroll
        for (int ct = 0; ct < 4; ++ct) {
            const int r8 = (ct * 16 + colL) * 8;
            bf16x8 a0 = *(const bf16x8*)&KB[cur][(r8 + (grp ^ c7)) * 8];
            bf16x8 a1 = *(const bf16x8*)&KB[cur][(r8 + (grp ^ 4 ^ c7)) * 8];
            floatx4 acc = (floatx4){0.f, 0.f, 0.f, 0.f};
            acc = MFMA16(a0, qf0, acc);
            acc = MFMA16(a1, qf1, acc);
            s[ct] = acc;
        }
        __builtin_amdgcn_s_setprio(0);
        // t = exp(s + lp)
#pragma unroll
        for (int ct = 0; ct < 4; ++ct) {
            float4v lv = *(const float4v*)&LP[cur][lpAddr(ct)];
            bf16x4 pw;
#pragma unroll
            for (int r = 0; r < 4; ++r) {
                float tv = __expf(s[ct][r] + lv[r]);
                ua += tv;
                pw[r] = (bf16)tv;
            }
            *(bf16x4*)&P[(colL * 64 + ct * 16 + grp * 4) ^ swz] = pw;
        }
        // PV from LDS V
        __builtin_amdgcn_s_setprio(1);
#pragma unroll
        for (int ks = 0; ks < 2; ++ks) {
            bf16x8 pb = *(const bf16x8*)&P[(colL * 64 + ks * 32 + grp * 8) ^ swz];
#pragma unroll
            for (int dt = 0; dt < 4; ++dt) {
                const int r8 = (dt * 16 + colL) * 8;
                bf16x8 vf = *(const bf16x8*)&Ush.p1.VB[cur][(r8 + ((ks * 4 + grp) ^ c7)) * 8];
                oT[dt] = MFMA16(vf, pb, oT[dt]);
            }
        }
        __builtin_amdgcn_s_setprio(0);
        __syncthreads();
    }

    // ---------------- U reduce + O write
    ua += __shfl_xor(ua, 16, 64);
    ua += __shfl_xor(ua, 32, 64);
    const float iu = 1.0f / ua;
#pragma unroll
    for (int dt = 0; dt < 4; ++dt) {
        bf16x4 ow;
#pragma unroll
        for (int r = 0; r < 4; ++r) ow[r] = (bf16)(oT[dt][r] * iu);
        *(bf16x4*)(O + ((size_t)b * S_ + q0 + colL) * DIM_ + h * HD_ + dt * 16 + grp * 4) = ow;
    }

    // ---------------- phase 2 prologue (FS aliases V/P space — safe after barrier)
    __syncthreads();
    stageK(0, 0);
    stageLP(0, 0);
    __syncthreads();

    // ---------------- phase 2: recompute, nt-write attn = exp(s+lp)*invU
    const float* Aout = attn_out + (size_t)bh * S_ * S_;
    for (int kt = 0; kt < 32; ++kt) {
        const int k0 = kt * 64;
        const int cur = kt & 1;
        if (kt < 31) {
            stageK(cur ^ 1, k0 + 64);
            stageLP(cur ^ 1, k0 + 64);
        }

        floatx4 s[4];
        __builtin_amdgcn_s_setprio(1);
#pragma unroll
        for (int ct = 0; ct < 4; ++ct) {
            const int r8 = (ct * 16 + colL) * 8;
            bf16x8 a0 = *(const bf16x8*)&KB[cur][(r8 + (grp ^ c7)) * 8];
            bf16x8 a1 = *(const bf16x8*)&KB[cur][(r8 + (grp ^ 4 ^ c7)) * 8];
            floatx4 acc = (floatx4){0.f, 0.f, 0.f, 0.f};
            acc = MFMA16(a0, qf0, acc);
            acc = MFMA16(a1, qf1, acc);
            s[ct] = acc;
        }
        __builtin_amdgcn_s_setprio(0);
        // stage f32 tile into wave-private LDS (row = q-in-wave, col = k-in-tile)
#pragma unroll
        for (int ct = 0; ct < 4; ++ct) {
            float4v lv = *(const float4v*)&LP[cur][lpAddr(ct)];
            float4v o;
#pragma unroll
            for (int r = 0; r < 4; ++r)
                o[r] = __expf(s[ct][r] + lv[r]) * iu;
            *(float4v*)&Ush.FS[wv][colL * 68 + ct * 16 + grp * 4] = o;
        }
        // transposed read-out: 4 rows x 256B contiguous, NON-TEMPORAL stores
#pragma unroll
        for (int it = 0; it < 4; ++it) {
            const int row = it * 4 + grp;
            float4v v = *(const float4v*)&Ush.FS[wv][row * 68 + colL * 4];
            __builtin_nontemporal_store(v,
                (float4v*)(Aout + (size_t)(q0 + row) * S_ + k0 + colL * 4));
        }
        __syncthreads();
    }
}

// ---------------------------------------------------------------- launch
extern "C" void kernel_launch(void* const* d_in, const int* in_sizes, int n_in,
                              void* d_out, int out_size, void* d_ws, size_t ws_size,
                              hipStream_t stream) {
    const float* q_x   = (const float*)d_in[0];
    const float* kv_x  = (const float*)d_in[1];
    const float* q_fr  = (const float*)d_in[2];
    const float* k_fr  = (const float*)d_in[3];
    const float* maskp = (const float*)d_in[4];
    const float* prior = (const float*)d_in[5];
    const float* Wq    = (const float*)d_in[6];
    const float* Wkv   = (const float*)d_in[7];
    const float* Wproj = (const float*)d_in[8];
    const float* bproj = (const float*)d_in[9];

    float* out_x    = (float*)d_out;                       // (B,S,DIM)
    float* out_attn = out_x + (size_t)B_ * S_ * DIM_;      // (B,H,S,S)

    char* w = (char*)d_ws;
    bf16* qx_b  = (bf16*)(w + (size_t)0);          //  8 MiB
    bf16* kvx_b = (bf16*)(w + ((size_t)8  << 20)); //  8 MiB
    bf16* wq_b  = (bf16*)(w + ((size_t)16 << 20)); //  2 MiB
    bf16* wkv_b = (bf16*)(w + ((size_t)18 << 20)); //  4 MiB
    bf16* wpj_b = (bf16*)(w + ((size_t)22 << 20)); //  2 MiB
    bf16* qp    = (bf16*)(w + ((size_t)24 << 20)); //  8 MiB  (B,S,DIM)
    bf16* kvp   = (bf16*)(w + ((size_t)32 << 20)); // 16 MiB  (B,S,2*DIM)
    bf16* qr    = (bf16*)(w + ((size_t)48 << 20)); //  8 MiB  (B,H,S,HD)
    bf16* kr    = (bf16*)(w + ((size_t)56 << 20)); //  8 MiB
    bf16* vt    = (bf16*)(w + ((size_t)64 << 20)); //  8 MiB  (B,H,HD,S)
    bf16* ob    = (bf16*)(w + ((size_t)72 << 20)); //  8 MiB  (B,S,DIM)
    float* lpb  = (float*)(w + ((size_t)96 << 20)); // 32 MiB  (B,S,S) f32

    // all conversions + lp in one kernel (nt loads: inputs read exactly once)
    prep_kernel<<<20480, 256, 0, stream>>>(q_x, kv_x, Wq, Wkv, Wproj, maskp, prior,
                                           qx_b, kvx_b, wq_b, wkv_b, wpj_b, lpb);

    // projections
    gemm_bt<0, 0><<<dim3(8, 32),  256, 0, stream>>>(qx_b,  wq_b,  qp,  nullptr, 4096, 1024, 1024);
    gemm_bt<0, 0><<<dim3(16, 32), 256, 0, stream>>>(kvx_b, wkv_b, kvp, nullptr, 4096, 2048, 1024);

    // RoPE (q,k) + V transpose in one kernel
    rope_vt_kernel<<<5120, 256, 0, stream>>>(qp, kvp, q_fr, k_fr, qr, kr, vt);

    // fused attention: O + attn in one kernel (XCD-swizzled grid)
    attn_fused<<<1024, 256, 0, stream>>>(qr, kr, vt, lpb, out_attn, ob);

    // output projection (nt f32 store: out_x never re-read)
    gemm_bt<1, 1><<<dim3(8, 32), 256, 0, stream>>>(ob, wpj_b, out_x, bproj, 4096, 1024, 1024);
}

// Round 15
// 358.402 us; speedup vs baseline: 1.3517x; 1.0276x over previous
//
#include <hip/hip_runtime.h>
#include <hip/hip_bf16.h>

typedef __bf16 bf16;
typedef __bf16 bf16x4 __attribute__((ext_vector_type(4)));
typedef __bf16 bf16x8 __attribute__((ext_vector_type(8)));
typedef float floatx4 __attribute__((ext_vector_type(4)));
typedef float float4v __attribute__((ext_vector_type(4)));

#define MFMA16(a, b, c) __builtin_amdgcn_mfma_f32_16x16x32_bf16(a, b, c, 0, 0, 0)

constexpr int B_ = 2, S_ = 2048, DIM_ = 1024, H_ = 16, HD_ = 64;
constexpr float SCALE_ = 0.125f;   // HD^-0.5
constexpr float EPS_ = 1e-8f;

// ---------------------------------------------------------------- helpers
__device__ __forceinline__ void gload_lds16(const void* g, void* l) {
    __builtin_amdgcn_global_load_lds(
        (const __attribute__((address_space(1))) void*)g,
        (__attribute__((address_space(3))) void*)l, 16, 0, 0);
}

// ---------------------------------------------------------------- prep: all f32->bf16 cvts + lp, one kernel
__global__ __launch_bounds__(256) void prep_kernel(const float* __restrict__ q_x,
                                                   const float* __restrict__ kv_x,
                                                   const float* __restrict__ Wq,
                                                   const float* __restrict__ Wkv,
                                                   const float* __restrict__ Wproj,
                                                   const float* __restrict__ mask,
                                                   const float* __restrict__ prior,
                                                   bf16* __restrict__ qx_b,
                                                   bf16* __restrict__ kvx_b,
                                                   bf16* __restrict__ wq_b,
                                                   bf16* __restrict__ wkv_b,
                                                   bf16* __restrict__ wpj_b,
                                                   float* __restrict__ lp) {
    const int blk = blockIdx.x, t = threadIdx.x;
    auto cvt = [&](const float* in, bf16* out, int base) {
        int i = base * 256 + t;
        float4v v = __builtin_nontemporal_load((const float4v*)in + i);
        bf16x4 o;
#pragma unroll
        for (int j = 0; j < 4; ++j) o[j] = (bf16)v[j];
        ((bf16x4*)out)[i] = o;
    };
    if (blk < 4096)        cvt(q_x,   qx_b,  blk);
    else if (blk < 8192)   cvt(kv_x,  kvx_b, blk - 4096);
    else if (blk < 9216)   cvt(Wq,    wq_b,  blk - 8192);
    else if (blk < 11264)  cvt(Wkv,   wkv_b, blk - 9216);
    else if (blk < 12288)  cvt(Wproj, wpj_b, blk - 11264);
    else {
        int i = (blk - 12288) * 256 + t;
        float4v m = __builtin_nontemporal_load((const float4v*)mask + i);
        float4v p = __builtin_nontemporal_load((const float4v*)prior + i);
        float4v o;
#pragma unroll
        for (int j = 0; j < 4; ++j) o[j] = m[j] + __logf(fmaxf(p[j], EPS_));
        ((float4v*)lp)[i] = o;
    }
}

// ---------------------------------------------------------------- GEMM 128x128 tile: C = A(MxK) * B(NxK)^T
template<int OUTF32, int BIASED>
__global__ __launch_bounds__(256) void gemm_bt(const bf16* __restrict__ A,
                                               const bf16* __restrict__ B,
                                               void* __restrict__ Cp,
                                               const float* __restrict__ bias,
                                               int M, int N, int K) {
    __shared__ bf16 As[128 * 64];
    __shared__ bf16 Bs[128 * 64];
    const int lane = threadIdx.x & 63, wid = threadIdx.x >> 6;
    const int colL = lane & 15, grp = lane >> 4;
    const int bm = blockIdx.y * 128, bn = blockIdx.x * 128;
    const int wr = wid >> 1, wc = wid & 1;

    floatx4 acc[4][4];
#pragma unroll
    for (int m = 0; m < 4; ++m)
#pragma unroll
        for (int n = 0; n < 4; ++n) acc[m][n] = (floatx4){0.f, 0.f, 0.f, 0.f};

    for (int k0 = 0; k0 < K; k0 += 64) {
#pragma unroll
        for (int i = 0; i < 4; ++i) {
            int c = wid * 256 + i * 64 + lane;
            int row = c >> 3, sub = c & 7;
            gload_lds16(A + (size_t)(bm + row) * K + k0 + sub * 8,
                        &As[(wid * 256 + i * 64) * 8]);
            gload_lds16(B + (size_t)(bn + row) * K + k0 + sub * 8,
                        &Bs[(wid * 256 + i * 64) * 8]);
        }
        __syncthreads();
#pragma unroll
        for (int ks = 0; ks < 2; ++ks) {
            bf16x8 af[4], bfr[4];
#pragma unroll
            for (int m = 0; m < 4; ++m)
                af[m] = *(const bf16x8*)(&As[(wr * 64 + m * 16 + colL) * 64 + ks * 32 + grp * 8]);
#pragma unroll
            for (int n = 0; n < 4; ++n)
                bfr[n] = *(const bf16x8*)(&Bs[(wc * 64 + n * 16 + colL) * 64 + ks * 32 + grp * 8]);
#pragma unroll
            for (int m = 0; m < 4; ++m)
#pragma unroll
                for (int n = 0; n < 4; ++n)
                    acc[m][n] = MFMA16(af[m], bfr[n], acc[m][n]);
        }
        __syncthreads();
    }

#pragma unroll
    for (int m = 0; m < 4; ++m)
#pragma unroll
        for (int n = 0; n < 4; ++n)
#pragma unroll
            for (int r = 0; r < 4; ++r) {
                int row = bm + wr * 64 + m * 16 + grp * 4 + r;
                int col = bn + wc * 64 + n * 16 + colL;
                float v = acc[m][n][r];
                if (BIASED) v += bias[col];
                if (OUTF32)
                    __builtin_nontemporal_store(v, (float*)Cp + (size_t)row * N + col);
                else
                    ((bf16*)Cp)[(size_t)row * N + col] = (bf16)v;
            }
}

// ---------------------------------------------------------------- GEMM 128x64 tile (small-N variant, 2x grid)
// Wave w: rows [w*32, w*32+32), cols 0..63. acc[2][4]. LDS 24KB.
template<int OUTF32, int BIASED>
__global__ __launch_bounds__(256) void gemm_bt64(const bf16* __restrict__ A,
                                                 const bf16* __restrict__ B,
                                                 void* __restrict__ Cp,
                                                 const float* __restrict__ bias,
                                                 int M, int N, int K) {
    __shared__ bf16 As[128 * 64];
    __shared__ bf16 Bs[64 * 64];
    const int tid = threadIdx.x;
    const int lane = tid & 63, wid = tid >> 6;
    const int colL = lane & 15, grp = lane >> 4;
    const int bm = blockIdx.y * 128, bn = blockIdx.x * 64;

    floatx4 acc[2][4];
#pragma unroll
    for (int m = 0; m < 2; ++m)
#pragma unroll
        for (int n = 0; n < 4; ++n) acc[m][n] = (floatx4){0.f, 0.f, 0.f, 0.f};

    for (int k0 = 0; k0 < K; k0 += 64) {
#pragma unroll
        for (int i = 0; i < 4; ++i) {          // A: 1024 chunks
            int c = wid * 256 + i * 64 + lane;
            int row = c >> 3, sub = c & 7;
            gload_lds16(A + (size_t)(bm + row) * K + k0 + sub * 8,
                        &As[(c & ~63) << 3]);
        }
#pragma unroll
        for (int i = 0; i < 2; ++i) {          // B: 512 chunks
            int c = i * 256 + tid;
            int row = c >> 3, sub = c & 7;
            gload_lds16(B + (size_t)(bn + row) * K + k0 + sub * 8,
                        &Bs[(c & ~63) << 3]);
        }
        __syncthreads();
#pragma unroll
        for (int ks = 0; ks < 2; ++ks) {
            bf16x8 af[2], bfr[4];
#pragma unroll
            for (int m = 0; m < 2; ++m)
                af[m] = *(const bf16x8*)(&As[(wid * 32 + m * 16 + colL) * 64 + ks * 32 + grp * 8]);
#pragma unroll
            for (int n = 0; n < 4; ++n)
                bfr[n] = *(const bf16x8*)(&Bs[(n * 16 + colL) * 64 + ks * 32 + grp * 8]);
#pragma unroll
            for (int m = 0; m < 2; ++m)
#pragma unroll
                for (int n = 0; n < 4; ++n)
                    acc[m][n] = MFMA16(af[m], bfr[n], acc[m][n]);
        }
        __syncthreads();
    }

#pragma unroll
    for (int m = 0; m < 2; ++m)
#pragma unroll
        for (int n = 0; n < 4; ++n)
#pragma unroll
            for (int r = 0; r < 4; ++r) {
                int row = bm + wid * 32 + m * 16 + grp * 4 + r;
                int col = bn + n * 16 + colL;
                float v = acc[m][n][r];
                if (BIASED) v += bias[col];
                if (OUTF32)
                    __builtin_nontemporal_store(v, (float*)Cp + (size_t)row * N + col);
                else
                    ((bf16*)Cp)[(size_t)row * N + col] = (bf16)v;
            }
}

// ---------------------------------------------------------------- rope (q,k) + vtrans, one kernel
__global__ __launch_bounds__(256) void rope_vt_kernel(const bf16* __restrict__ qp,
                                                      const bf16* __restrict__ kvp,
                                                      const float* __restrict__ q_fr,
                                                      const float* __restrict__ k_fr,
                                                      bf16* __restrict__ qr,
                                                      bf16* __restrict__ kr,
                                                      bf16* __restrict__ vt) {
    __shared__ bf16 tile[64][66];
    const int blk = blockIdx.x;
    if (blk < 4096) {
        const bf16* in   = (blk < 2048) ? qp : kvp;
        const float* fr  = (blk < 2048) ? q_fr : k_fr;
        bf16* out        = (blk < 2048) ? qr : kr;
        const int in_ld  = (blk < 2048) ? 1024 : 2048;
        const float scale = (blk < 2048) ? SCALE_ : 1.0f;
        int tid = (blk & 2047) * 256 + threadIdx.x;
        int j = tid & 7, h = (tid >> 3) & 15, s = (tid >> 7) & 2047, b = tid >> 18;
        bf16x8 x = *(const bf16x8*)(in + (size_t)(b * 2048 + s) * in_ld + h * 64 + j * 8);
        const float* f = fr + (size_t)(b * 2048 + s) * 64 + j * 4;
        bf16x8 o;
#pragma unroll
        for (int i = 0; i < 4; ++i) {
            float c = f[i], sn = f[32 + i];
            float x0 = (float)x[2 * i], x1 = (float)x[2 * i + 1];
            o[2 * i]     = (bf16)((x0 * c - x1 * sn) * scale);
            o[2 * i + 1] = (bf16)((x0 * sn + x1 * c) * scale);
        }
        *(bf16x8*)(out + ((size_t)(b * 16 + h) * 2048 + s) * 64 + j * 8) = o;
    } else {
        const int bid = blk - 4096;
        const int sb = bid & 31, h = (bid >> 5) & 15, b = bid >> 9;
        const int tid = threadIdx.x;
#pragma unroll
        for (int i = 0; i < 2; ++i) {
            int c = tid + i * 256;
            int row = c >> 3, sub = c & 7;
            bf16x8 x = *(const bf16x8*)(kvp + (size_t)(b * 2048 + sb * 64 + row) * 2048
                                        + 1024 + h * 64 + sub * 8);
#pragma unroll
            for (int k = 0; k < 8; ++k) tile[row][sub * 8 + k] = x[k];
        }
        __syncthreads();
#pragma unroll
        for (int i = 0; i < 2; ++i) {
            int c = tid + i * 256;
            int drow = c >> 3, sub = c & 7;
            bf16x8 o;
#pragma unroll
            for (int k = 0; k < 8; ++k) o[k] = tile[sub * 8 + k][drow];
            *(bf16x8*)(vt + ((size_t)(b * 16 + h) * 64 + drow) * 2048 + sb * 64 + sub * 8) = o;
        }
    }
}

// ---------------------------------------------------------------- fused attention, two-phase, shift-free
// R13/R14 structure (measured best). Unchanged.
__global__ __launch_bounds__(256) void attn_fused(const bf16* __restrict__ Qr,
                                                  const bf16* __restrict__ Kr,
                                                  const bf16* __restrict__ Vt,
                                                  const float* __restrict__ lp,
                                                  float* __restrict__ attn_out,
                                                  bf16* __restrict__ O) {
    __shared__ bf16 KB[2][4096];
    __shared__ float LP[2][4096];       // 64 rows x 64 f32, dbuf
    union ShU {
        struct { bf16 VB[2][4096]; bf16 P[4][1024]; } p1;   // phase 1
        float FS[4][1088];                                   // phase 2: 16 x 68 per wave
    };
    __shared__ ShU Ush;

    const int tid = threadIdx.x;
    const int lane = tid & 63, wv = tid >> 6;
    const int colL = lane & 15, grp = lane >> 4;
    // XCD swizzle: all 16 heads of a (b,qb) pair on one XCD
    const int n = blockIdx.x;
    const int x = n & 7, j = n >> 3;
    const int h = j & 15;
    const int pp = (j >> 4) * 8 + x;
    const int b = pp >> 5, qb = pp & 31;
    const int bh = b * H_ + h;
    const int q0 = qb * 64 + wv * 16;
    const int rowL = wv * 16 + colL;        // block-level q-row of this lane

    const bf16* Qbase = Qr + ((size_t)bh * S_ + q0) * HD_;
    const bf16* Kbase = Kr + (size_t)bh * S_ * HD_;
    const bf16* Vbase = Vt + (size_t)bh * HD_ * S_;
    const float* LPbase = lp + ((size_t)b * S_ + qb * 64) * S_;

    bf16x8 qf0 = *(const bf16x8*)(Qbase + (size_t)colL * HD_ + grp * 8);
    bf16x8 qf1 = *(const bf16x8*)(Qbase + (size_t)colL * HD_ + 32 + grp * 8);

    bf16* P = Ush.p1.P[wv];
    const int swz = (colL & 7) << 3;
    const int c7 = colL & 7;

    auto stageK = [&](int buf, int k0) {
#pragma unroll
        for (int i = 0; i < 2; ++i) {
            int c = i * 256 + tid;
            int row = c >> 3, sub = c & 7;
            gload_lds16(Kbase + (size_t)(k0 + row) * HD_ + ((sub ^ (row & 7)) << 3),
                        &KB[buf][(c & ~63) << 3]);
        }
    };
    auto stageV = [&](int buf, int k0) {
#pragma unroll
        for (int i = 0; i < 2; ++i) {
            int c = i * 256 + tid;
            int row = c >> 3, sub = c & 7;
            gload_lds16(Vbase + (size_t)row * S_ + k0 + ((sub ^ (row & 7)) << 3),
                        &Ush.p1.VB[buf][(c & ~63) << 3]);
        }
    };
    // lp tile: 64 rows x 64 f32 = 1024 x 16B chunks; row = c>>4, col16 = c&15
    auto stageLP = [&](int buf, int k0) {
#pragma unroll
        for (int i = 0; i < 4; ++i) {
            int c = i * 256 + tid;
            int row = c >> 4, col16 = c & 15;
            gload_lds16(LPbase + (size_t)row * S_ + k0 + ((col16 ^ (row & 7)) << 2),
                        &LP[buf][(c & ~63) << 2]);
        }
    };
    // lane's lp read address (word units) for sub-tile ct
    auto lpAddr = [&](int ct) {
        return rowL * 64 + (((ct * 4 + grp) ^ (rowL & 7)) << 2);
    };

    float ua = 0.f;
    floatx4 oT[4];
#pragma unroll
    for (int dt = 0; dt < 4; ++dt) oT[dt] = (floatx4){0.f, 0.f, 0.f, 0.f};

    // ---------------- phase 1 prologue
    stageK(0, 0);
    stageV(0, 0);
    stageLP(0, 0);
    __syncthreads();

    // ---------------- phase 1: U + O accumulation
    for (int kt = 0; kt < 32; ++kt) {
        const int k0 = kt * 64;
        const int cur = kt & 1;
        if (kt < 31) {
            stageK(cur ^ 1, k0 + 64);
            stageV(cur ^ 1, k0 + 64);
            stageLP(cur ^ 1, k0 + 64);
        }

        // QK^T from LDS
        floatx4 s[4];
        __builtin_amdgcn_s_setprio(1);
#pragma unroll
        for (int ct = 0; ct < 4; ++ct) {
            const int r8 = (ct * 16 + colL) * 8;
            bf16x8 a0 = *(const bf16x8*)&KB[cur][(r8 + (grp ^ c7)) * 8];
            bf16x8 a1 = *(const bf16x8*)&KB[cur][(r8 + (grp ^ 4 ^ c7)) * 8];
            floatx4 acc = (floatx4){0.f, 0.f, 0.f, 0.f};
            acc = MFMA16(a0, qf0, acc);
            acc = MFMA16(a1, qf1, acc);
            s[ct] = acc;
        }
        __builtin_amdgcn_s_setprio(0);
        // t = exp(s + lp)
#pragma unroll
        for (int ct = 0; ct < 4; ++ct) {
            float4v lv = *(const float4v*)&LP[cur][lpAddr(ct)];
            bf16x4 pw;
#pragma unroll
            for (int r = 0; r < 4; ++r) {
                float tv = __expf(s[ct][r] + lv[r]);
                ua += tv;
                pw[r] = (bf16)tv;
            }
            *(bf16x4*)&P[(colL * 64 + ct * 16 + grp * 4) ^ swz] = pw;
        }
        // PV from LDS V
        __builtin_amdgcn_s_setprio(1);
#pragma unroll
        for (int ks = 0; ks < 2; ++ks) {
            bf16x8 pb = *(const bf16x8*)&P[(colL * 64 + ks * 32 + grp * 8) ^ swz];
#pragma unroll
            for (int dt = 0; dt < 4; ++dt) {
                const int r8 = (dt * 16 + colL) * 8;
                bf16x8 vf = *(const bf16x8*)&Ush.p1.VB[cur][(r8 + ((ks * 4 + grp) ^ c7)) * 8];
                oT[dt] = MFMA16(vf, pb, oT[dt]);
            }
        }
        __builtin_amdgcn_s_setprio(0);
        __syncthreads();
    }

    // ---------------- U reduce + O write
    ua += __shfl_xor(ua, 16, 64);
    ua += __shfl_xor(ua, 32, 64);
    const float iu = 1.0f / ua;
#pragma unroll
    for (int dt = 0; dt < 4; ++dt) {
        bf16x4 ow;
#pragma unroll
        for (int r = 0; r < 4; ++r) ow[r] = (bf16)(oT[dt][r] * iu);
        *(bf16x4*)(O + ((size_t)b * S_ + q0 + colL) * DIM_ + h * HD_ + dt * 16 + grp * 4) = ow;
    }

    // ---------------- phase 2 prologue (FS aliases V/P space — safe after barrier)
    __syncthreads();
    stageK(0, 0);
    stageLP(0, 0);
    __syncthreads();

    // ---------------- phase 2: recompute, nt-write attn = exp(s+lp)*invU
    const float* Aout = attn_out + (size_t)bh * S_ * S_;
    for (int kt = 0; kt < 32; ++kt) {
        const int k0 = kt * 64;
        const int cur = kt & 1;
        if (kt < 31) {
            stageK(cur ^ 1, k0 + 64);
            stageLP(cur ^ 1, k0 + 64);
        }

        floatx4 s[4];
        __builtin_amdgcn_s_setprio(1);
#pragma unroll
        for (int ct = 0; ct < 4; ++ct) {
            const int r8 = (ct * 16 + colL) * 8;
            bf16x8 a0 = *(const bf16x8*)&KB[cur][(r8 + (grp ^ c7)) * 8];
            bf16x8 a1 = *(const bf16x8*)&KB[cur][(r8 + (grp ^ 4 ^ c7)) * 8];
            floatx4 acc = (floatx4){0.f, 0.f, 0.f, 0.f};
            acc = MFMA16(a0, qf0, acc);
            acc = MFMA16(a1, qf1, acc);
            s[ct] = acc;
        }
        __builtin_amdgcn_s_setprio(0);
        // stage f32 tile into wave-private LDS (row = q-in-wave, col = k-in-tile)
#pragma unroll
        for (int ct = 0; ct < 4; ++ct) {
            float4v lv = *(const float4v*)&LP[cur][lpAddr(ct)];
            float4v o;
#pragma unroll
            for (int r = 0; r < 4; ++r)
                o[r] = __expf(s[ct][r] + lv[r]) * iu;
            *(float4v*)&Ush.FS[wv][colL * 68 + ct * 16 + grp * 4] = o;
        }
        // transposed read-out: 4 rows x 256B contiguous, NON-TEMPORAL stores
#pragma unroll
        for (int it = 0; it < 4; ++it) {
            const int row = it * 4 + grp;
            float4v v = *(const float4v*)&Ush.FS[wv][row * 68 + colL * 4];
            __builtin_nontemporal_store(v,
                (float4v*)(Aout + (size_t)(q0 + row) * S_ + k0 + colL * 4));
        }
        __syncthreads();
    }
}

// ---------------------------------------------------------------- launch
extern "C" void kernel_launch(void* const* d_in, const int* in_sizes, int n_in,
                              void* d_out, int out_size, void* d_ws, size_t ws_size,
                              hipStream_t stream) {
    const float* q_x   = (const float*)d_in[0];
    const float* kv_x  = (const float*)d_in[1];
    const float* q_fr  = (const float*)d_in[2];
    const float* k_fr  = (const float*)d_in[3];
    const float* maskp = (const float*)d_in[4];
    const float* prior = (const float*)d_in[5];
    const float* Wq    = (const float*)d_in[6];
    const float* Wkv   = (const float*)d_in[7];
    const float* Wproj = (const float*)d_in[8];
    const float* bproj = (const float*)d_in[9];

    float* out_x    = (float*)d_out;                       // (B,S,DIM)
    float* out_attn = out_x + (size_t)B_ * S_ * DIM_;      // (B,H,S,S)

    char* w = (char*)d_ws;
    bf16* qx_b  = (bf16*)(w + (size_t)0);          //  8 MiB
    bf16* kvx_b = (bf16*)(w + ((size_t)8  << 20)); //  8 MiB
    bf16* wq_b  = (bf16*)(w + ((size_t)16 << 20)); //  2 MiB
    bf16* wkv_b = (bf16*)(w + ((size_t)18 << 20)); //  4 MiB
    bf16* wpj_b = (bf16*)(w + ((size_t)22 << 20)); //  2 MiB
    bf16* qp    = (bf16*)(w + ((size_t)24 << 20)); //  8 MiB  (B,S,DIM)
    bf16* kvp   = (bf16*)(w + ((size_t)32 << 20)); // 16 MiB  (B,S,2*DIM)
    bf16* qr    = (bf16*)(w + ((size_t)48 << 20)); //  8 MiB  (B,H,S,HD)
    bf16* kr    = (bf16*)(w + ((size_t)56 << 20)); //  8 MiB
    bf16* vt    = (bf16*)(w + ((size_t)64 << 20)); //  8 MiB  (B,H,HD,S)
    bf16* ob    = (bf16*)(w + ((size_t)72 << 20)); //  8 MiB  (B,S,DIM)
    float* lpb  = (float*)(w + ((size_t)96 << 20)); // 32 MiB  (B,S,S) f32

    // all conversions + lp in one kernel (nt loads: inputs read exactly once)
    prep_kernel<<<20480, 256, 0, stream>>>(q_x, kv_x, Wq, Wkv, Wproj, maskp, prior,
                                           qx_b, kvx_b, wq_b, wkv_b, wpj_b, lpb);

    // projections: q uses 128x64 tile (512 blocks = 2/CU); kv stays 128x128
    gemm_bt64<0, 0><<<dim3(16, 32), 256, 0, stream>>>(qx_b,  wq_b,  qp,  nullptr, 4096, 1024, 1024);
    gemm_bt  <0, 0><<<dim3(16, 32), 256, 0, stream>>>(kvx_b, wkv_b, kvp, nullptr, 4096, 2048, 1024);

    // RoPE (q,k) + V transpose in one kernel
    rope_vt_kernel<<<5120, 256, 0, stream>>>(qp, kvp, q_fr, k_fr, qr, kr, vt);

    // fused attention: O + attn in one kernel (XCD-swizzled grid)
    attn_fused<<<1024, 256, 0, stream>>>(qr, kr, vt, lpb, out_attn, ob);

    // output projection: 128x64 tile, nt f32 stores
    gemm_bt64<1, 1><<<dim3(16, 32), 256, 0, stream>>>(ob, wpj_b, out_x, bproj, 4096, 1024, 1024);
}

// Round 16
// 358.255 us; speedup vs baseline: 1.3522x; 1.0004x over previous
//
#include <hip/hip_runtime.h>
#include <hip/hip_bf16.h>

typedef __bf16 bf16;
typedef __bf16 bf16x4 __attribute__((ext_vector_type(4)));
typedef __bf16 bf16x8 __attribute__((ext_vector_type(8)));
typedef float floatx4 __attribute__((ext_vector_type(4)));
typedef float float4v __attribute__((ext_vector_type(4)));

#define MFMA16(a, b, c) __builtin_amdgcn_mfma_f32_16x16x32_bf16(a, b, c, 0, 0, 0)

constexpr int B_ = 2, S_ = 2048, DIM_ = 1024, H_ = 16, HD_ = 64;
constexpr float SCALE_ = 0.125f;   // HD^-0.5
constexpr float EPS_ = 1e-8f;

// ---------------------------------------------------------------- helpers
__device__ __forceinline__ void gload_lds16(const void* g, void* l) {
    __builtin_amdgcn_global_load_lds(
        (const __attribute__((address_space(1))) void*)g,
        (__attribute__((address_space(3))) void*)l, 16, 0, 0);
}

// ---------------------------------------------------------------- prep: all f32->bf16 cvts + lp, one kernel
// 2 float4 per thread. block ranges (of 512 f32x4 each... i.e. 2048 f32/blk):
// [0,2048) q_x | [2048,4096) kv_x | [4096,4608) Wq | [4608,5632) Wkv
// | [5632,6144) Wproj | [6144,10240) lp
__global__ __launch_bounds__(256) void prep_kernel(const float* __restrict__ q_x,
                                                   const float* __restrict__ kv_x,
                                                   const float* __restrict__ Wq,
                                                   const float* __restrict__ Wkv,
                                                   const float* __restrict__ Wproj,
                                                   const float* __restrict__ mask,
                                                   const float* __restrict__ prior,
                                                   bf16* __restrict__ qx_b,
                                                   bf16* __restrict__ kvx_b,
                                                   bf16* __restrict__ wq_b,
                                                   bf16* __restrict__ wkv_b,
                                                   bf16* __restrict__ wpj_b,
                                                   float* __restrict__ lp) {
    const int blk = blockIdx.x, t = threadIdx.x;
    auto cvt = [&](const float* in, bf16* out, int base) {
#pragma unroll
        for (int u = 0; u < 2; ++u) {
            int i = base * 512 + u * 256 + t;
            float4v v = __builtin_nontemporal_load((const float4v*)in + i);
            bf16x4 o;
#pragma unroll
            for (int j = 0; j < 4; ++j) o[j] = (bf16)v[j];
            ((bf16x4*)out)[i] = o;
        }
    };
    if (blk < 2048)       cvt(q_x,   qx_b,  blk);
    else if (blk < 4096)  cvt(kv_x,  kvx_b, blk - 2048);
    else if (blk < 4608)  cvt(Wq,    wq_b,  blk - 4096);
    else if (blk < 5632)  cvt(Wkv,   wkv_b, blk - 4608);
    else if (blk < 6144)  cvt(Wproj, wpj_b, blk - 5632);
    else {
#pragma unroll
        for (int u = 0; u < 2; ++u) {
            int i = (blk - 6144) * 512 + u * 256 + t;
            float4v m = __builtin_nontemporal_load((const float4v*)mask + i);
            float4v p = __builtin_nontemporal_load((const float4v*)prior + i);
            float4v o;
#pragma unroll
            for (int j = 0; j < 4; ++j) o[j] = m[j] + __logf(fmaxf(p[j], EPS_));
            ((float4v*)lp)[i] = o;
        }
    }
}

// ---------------------------------------------------------------- GEMM 128x64 tile, XCD-chunked 1D grid
// C = A(MxK) * B(NxK)^T. Wave w: rows [w*32,w*32+32), cols 0..63. LDS 24KB.
// grid = (M/128)*(N/64) blocks, must be divisible by 8; blocks sharing an
// A-panel (same bm) are placed contiguously on one XCD for L2 reuse.
template<int OUTF32, int BIASED>
__global__ __launch_bounds__(256) void gemm_bt64(const bf16* __restrict__ A,
                                                 const bf16* __restrict__ B,
                                                 void* __restrict__ Cp,
                                                 const float* __restrict__ bias,
                                                 int M, int N, int K) {
    __shared__ bf16 As[128 * 64];
    __shared__ bf16 Bs[64 * 64];
    const int tid = threadIdx.x;
    const int lane = tid & 63, wid = tid >> 6;
    const int colL = lane & 15, grp = lane >> 4;
    // XCD-chunked swizzle: per-XCD contiguous range of (bm-major) work
    const int nwg = gridDim.x, cpx = nwg >> 3;
    const int wg = (blockIdx.x & 7) * cpx + (blockIdx.x >> 3);
    const int nbn = N >> 6;
    const int bm = (wg / nbn) * 128, bn = (wg % nbn) * 64;

    floatx4 acc[2][4];
#pragma unroll
    for (int m = 0; m < 2; ++m)
#pragma unroll
        for (int n = 0; n < 4; ++n) acc[m][n] = (floatx4){0.f, 0.f, 0.f, 0.f};

    for (int k0 = 0; k0 < K; k0 += 64) {
#pragma unroll
        for (int i = 0; i < 4; ++i) {          // A: 1024 chunks
            int c = wid * 256 + i * 64 + lane;
            int row = c >> 3, sub = c & 7;
            gload_lds16(A + (size_t)(bm + row) * K + k0 + sub * 8,
                        &As[(c & ~63) << 3]);
        }
#pragma unroll
        for (int i = 0; i < 2; ++i) {          // B: 512 chunks
            int c = i * 256 + tid;
            int row = c >> 3, sub = c & 7;
            gload_lds16(B + (size_t)(bn + row) * K + k0 + sub * 8,
                        &Bs[(c & ~63) << 3]);
        }
        __syncthreads();
#pragma unroll
        for (int ks = 0; ks < 2; ++ks) {
            bf16x8 af[2], bfr[4];
#pragma unroll
            for (int m = 0; m < 2; ++m)
                af[m] = *(const bf16x8*)(&As[(wid * 32 + m * 16 + colL) * 64 + ks * 32 + grp * 8]);
#pragma unroll
            for (int n = 0; n < 4; ++n)
                bfr[n] = *(const bf16x8*)(&Bs[(n * 16 + colL) * 64 + ks * 32 + grp * 8]);
#pragma unroll
            for (int m = 0; m < 2; ++m)
#pragma unroll
                for (int n = 0; n < 4; ++n)
                    acc[m][n] = MFMA16(af[m], bfr[n], acc[m][n]);
        }
        __syncthreads();
    }

#pragma unroll
    for (int m = 0; m < 2; ++m)
#pragma unroll
        for (int n = 0; n < 4; ++n)
#pragma unroll
            for (int r = 0; r < 4; ++r) {
                int row = bm + wid * 32 + m * 16 + grp * 4 + r;
                int col = bn + n * 16 + colL;
                float v = acc[m][n][r];
                if (BIASED) v += bias[col];
                if (OUTF32)
                    __builtin_nontemporal_store(v, (float*)Cp + (size_t)row * N + col);
                else
                    ((bf16*)Cp)[(size_t)row * N + col] = (bf16)v;
            }
}

// ---------------------------------------------------------------- rope (q,k) + vtrans, one kernel
__global__ __launch_bounds__(256) void rope_vt_kernel(const bf16* __restrict__ qp,
                                                      const bf16* __restrict__ kvp,
                                                      const float* __restrict__ q_fr,
                                                      const float* __restrict__ k_fr,
                                                      bf16* __restrict__ qr,
                                                      bf16* __restrict__ kr,
                                                      bf16* __restrict__ vt) {
    __shared__ bf16 tile[64][66];
    const int blk = blockIdx.x;
    if (blk < 4096) {
        const bf16* in   = (blk < 2048) ? qp : kvp;
        const float* fr  = (blk < 2048) ? q_fr : k_fr;
        bf16* out        = (blk < 2048) ? qr : kr;
        const int in_ld  = (blk < 2048) ? 1024 : 2048;
        const float scale = (blk < 2048) ? SCALE_ : 1.0f;
        int tid = (blk & 2047) * 256 + threadIdx.x;
        int j = tid & 7, h = (tid >> 3) & 15, s = (tid >> 7) & 2047, b = tid >> 18;
        bf16x8 x = *(const bf16x8*)(in + (size_t)(b * 2048 + s) * in_ld + h * 64 + j * 8);
        const float* f = fr + (size_t)(b * 2048 + s) * 64 + j * 4;
        bf16x8 o;
#pragma unroll
        for (int i = 0; i < 4; ++i) {
            float c = f[i], sn = f[32 + i];
            float x0 = (float)x[2 * i], x1 = (float)x[2 * i + 1];
            o[2 * i]     = (bf16)((x0 * c - x1 * sn) * scale);
            o[2 * i + 1] = (bf16)((x0 * sn + x1 * c) * scale);
        }
        *(bf16x8*)(out + ((size_t)(b * 16 + h) * 2048 + s) * 64 + j * 8) = o;
    } else {
        const int bid = blk - 4096;
        const int sb = bid & 31, h = (bid >> 5) & 15, b = bid >> 9;
        const int tid = threadIdx.x;
#pragma unroll
        for (int i = 0; i < 2; ++i) {
            int c = tid + i * 256;
            int row = c >> 3, sub = c & 7;
            bf16x8 x = *(const bf16x8*)(kvp + (size_t)(b * 2048 + sb * 64 + row) * 2048
                                        + 1024 + h * 64 + sub * 8);
#pragma unroll
            for (int k = 0; k < 8; ++k) tile[row][sub * 8 + k] = x[k];
        }
        __syncthreads();
#pragma unroll
        for (int i = 0; i < 2; ++i) {
            int c = tid + i * 256;
            int drow = c >> 3, sub = c & 7;
            bf16x8 o;
#pragma unroll
            for (int k = 0; k < 8; ++k) o[k] = tile[sub * 8 + k][drow];
            *(bf16x8*)(vt + ((size_t)(b * 16 + h) * 64 + drow) * 2048 + sb * 64 + sub * 8) = o;
        }
    }
}

// ---------------------------------------------------------------- fused attention, two-phase, shift-free
// R13/R15 structure (measured best). Unchanged.
__global__ __launch_bounds__(256) void attn_fused(const bf16* __restrict__ Qr,
                                                  const bf16* __restrict__ Kr,
                                                  const bf16* __restrict__ Vt,
                                                  const float* __restrict__ lp,
                                                  float* __restrict__ attn_out,
                                                  bf16* __restrict__ O) {
    __shared__ bf16 KB[2][4096];
    __shared__ float LP[2][4096];       // 64 rows x 64 f32, dbuf
    union ShU {
        struct { bf16 VB[2][4096]; bf16 P[4][1024]; } p1;   // phase 1
        float FS[4][1088];                                   // phase 2: 16 x 68 per wave
    };
    __shared__ ShU Ush;

    const int tid = threadIdx.x;
    const int lane = tid & 63, wv = tid >> 6;
    const int colL = lane & 15, grp = lane >> 4;
    // XCD swizzle: all 16 heads of a (b,qb) pair on one XCD
    const int n = blockIdx.x;
    const int x = n & 7, j = n >> 3;
    const int h = j & 15;
    const int pp = (j >> 4) * 8 + x;
    const int b = pp >> 5, qb = pp & 31;
    const int bh = b * H_ + h;
    const int q0 = qb * 64 + wv * 16;
    const int rowL = wv * 16 + colL;        // block-level q-row of this lane

    const bf16* Qbase = Qr + ((size_t)bh * S_ + q0) * HD_;
    const bf16* Kbase = Kr + (size_t)bh * S_ * HD_;
    const bf16* Vbase = Vt + (size_t)bh * HD_ * S_;
    const float* LPbase = lp + ((size_t)b * S_ + qb * 64) * S_;

    bf16x8 qf0 = *(const bf16x8*)(Qbase + (size_t)colL * HD_ + grp * 8);
    bf16x8 qf1 = *(const bf16x8*)(Qbase + (size_t)colL * HD_ + 32 + grp * 8);

    bf16* P = Ush.p1.P[wv];
    const int swz = (colL & 7) << 3;
    const int c7 = colL & 7;

    auto stageK = [&](int buf, int k0) {
#pragma unroll
        for (int i = 0; i < 2; ++i) {
            int c = i * 256 + tid;
            int row = c >> 3, sub = c & 7;
            gload_lds16(Kbase + (size_t)(k0 + row) * HD_ + ((sub ^ (row & 7)) << 3),
                        &KB[buf][(c & ~63) << 3]);
        }
    };
    auto stageV = [&](int buf, int k0) {
#pragma unroll
        for (int i = 0; i < 2; ++i) {
            int c = i * 256 + tid;
            int row = c >> 3, sub = c & 7;
            gload_lds16(Vbase + (size_t)row * S_ + k0 + ((sub ^ (row & 7)) << 3),
                        &Ush.p1.VB[buf][(c & ~63) << 3]);
        }
    };
    // lp tile: 64 rows x 64 f32 = 1024 x 16B chunks; row = c>>4, col16 = c&15
    auto stageLP = [&](int buf, int k0) {
#pragma unroll
        for (int i = 0; i < 4; ++i) {
            int c = i * 256 + tid;
            int row = c >> 4, col16 = c & 15;
            gload_lds16(LPbase + (size_t)row * S_ + k0 + ((col16 ^ (row & 7)) << 2),
                        &LP[buf][(c & ~63) << 2]);
        }
    };
    // lane's lp read address (word units) for sub-tile ct
    auto lpAddr = [&](int ct) {
        return rowL * 64 + (((ct * 4 + grp) ^ (rowL & 7)) << 2);
    };

    float ua = 0.f;
    floatx4 oT[4];
#pragma unroll
    for (int dt = 0; dt < 4; ++dt) oT[dt] = (floatx4){0.f, 0.f, 0.f, 0.f};

    // ---------------- phase 1 prologue
    stageK(0, 0);
    stageV(0, 0);
    stageLP(0, 0);
    __syncthreads();

    // ---------------- phase 1: U + O accumulation
    for (int kt = 0; kt < 32; ++kt) {
        const int k0 = kt * 64;
        const int cur = kt & 1;
        if (kt < 31) {
            stageK(cur ^ 1, k0 + 64);
            stageV(cur ^ 1, k0 + 64);
            stageLP(cur ^ 1, k0 + 64);
        }

        // QK^T from LDS
        floatx4 s[4];
        __builtin_amdgcn_s_setprio(1);
#pragma unroll
        for (int ct = 0; ct < 4; ++ct) {
            const int r8 = (ct * 16 + colL) * 8;
            bf16x8 a0 = *(const bf16x8*)&KB[cur][(r8 + (grp ^ c7)) * 8];
            bf16x8 a1 = *(const bf16x8*)&KB[cur][(r8 + (grp ^ 4 ^ c7)) * 8];
            floatx4 acc = (floatx4){0.f, 0.f, 0.f, 0.f};
            acc = MFMA16(a0, qf0, acc);
            acc = MFMA16(a1, qf1, acc);
            s[ct] = acc;
        }
        __builtin_amdgcn_s_setprio(0);
        // t = exp(s + lp)
#pragma unroll
        for (int ct = 0; ct < 4; ++ct) {
            float4v lv = *(const float4v*)&LP[cur][lpAddr(ct)];
            bf16x4 pw;
#pragma unroll
            for (int r = 0; r < 4; ++r) {
                float tv = __expf(s[ct][r] + lv[r]);
                ua += tv;
                pw[r] = (bf16)tv;
            }
            *(bf16x4*)&P[(colL * 64 + ct * 16 + grp * 4) ^ swz] = pw;
        }
        // PV from LDS V
        __builtin_amdgcn_s_setprio(1);
#pragma unroll
        for (int ks = 0; ks < 2; ++ks) {
            bf16x8 pb = *(const bf16x8*)&P[(colL * 64 + ks * 32 + grp * 8) ^ swz];
#pragma unroll
            for (int dt = 0; dt < 4; ++dt) {
                const int r8 = (dt * 16 + colL) * 8;
                bf16x8 vf = *(const bf16x8*)&Ush.p1.VB[cur][(r8 + ((ks * 4 + grp) ^ c7)) * 8];
                oT[dt] = MFMA16(vf, pb, oT[dt]);
            }
        }
        __builtin_amdgcn_s_setprio(0);
        __syncthreads();
    }

    // ---------------- U reduce + O write
    ua += __shfl_xor(ua, 16, 64);
    ua += __shfl_xor(ua, 32, 64);
    const float iu = 1.0f / ua;
#pragma unroll
    for (int dt = 0; dt < 4; ++dt) {
        bf16x4 ow;
#pragma unroll
        for (int r = 0; r < 4; ++r) ow[r] = (bf16)(oT[dt][r] * iu);
        *(bf16x4*)(O + ((size_t)b * S_ + q0 + colL) * DIM_ + h * HD_ + dt * 16 + grp * 4) = ow;
    }

    // ---------------- phase 2 prologue (FS aliases V/P space — safe after barrier)
    __syncthreads();
    stageK(0, 0);
    stageLP(0, 0);
    __syncthreads();

    // ---------------- phase 2: recompute, nt-write attn = exp(s+lp)*invU
    const float* Aout = attn_out + (size_t)bh * S_ * S_;
    for (int kt = 0; kt < 32; ++kt) {
        const int k0 = kt * 64;
        const int cur = kt & 1;
        if (kt < 31) {
            stageK(cur ^ 1, k0 + 64);
            stageLP(cur ^ 1, k0 + 64);
        }

        floatx4 s[4];
        __builtin_amdgcn_s_setprio(1);
#pragma unroll
        for (int ct = 0; ct < 4; ++ct) {
            const int r8 = (ct * 16 + colL) * 8;
            bf16x8 a0 = *(const bf16x8*)&KB[cur][(r8 + (grp ^ c7)) * 8];
            bf16x8 a1 = *(const bf16x8*)&KB[cur][(r8 + (grp ^ 4 ^ c7)) * 8];
            floatx4 acc = (floatx4){0.f, 0.f, 0.f, 0.f};
            acc = MFMA16(a0, qf0, acc);
            acc = MFMA16(a1, qf1, acc);
            s[ct] = acc;
        }
        __builtin_amdgcn_s_setprio(0);
        // stage f32 tile into wave-private LDS (row = q-in-wave, col = k-in-tile)
#pragma unroll
        for (int ct = 0; ct < 4; ++ct) {
            float4v lv = *(const float4v*)&LP[cur][lpAddr(ct)];
            float4v o;
#pragma unroll
            for (int r = 0; r < 4; ++r)
                o[r] = __expf(s[ct][r] + lv[r]) * iu;
            *(float4v*)&Ush.FS[wv][colL * 68 + ct * 16 + grp * 4] = o;
        }
        // transposed read-out: 4 rows x 256B contiguous, NON-TEMPORAL stores
#pragma unroll
        for (int it = 0; it < 4; ++it) {
            const int row = it * 4 + grp;
            float4v v = *(const float4v*)&Ush.FS[wv][row * 68 + colL * 4];
            __builtin_nontemporal_store(v,
                (float4v*)(Aout + (size_t)(q0 + row) * S_ + k0 + colL * 4));
        }
        __syncthreads();
    }
}

// ---------------------------------------------------------------- launch
extern "C" void kernel_launch(void* const* d_in, const int* in_sizes, int n_in,
                              void* d_out, int out_size, void* d_ws, size_t ws_size,
                              hipStream_t stream) {
    const float* q_x   = (const float*)d_in[0];
    const float* kv_x  = (const float*)d_in[1];
    const float* q_fr  = (const float*)d_in[2];
    const float* k_fr  = (const float*)d_in[3];
    const float* maskp = (const float*)d_in[4];
    const float* prior = (const float*)d_in[5];
    const float* Wq    = (const float*)d_in[6];
    const float* Wkv   = (const float*)d_in[7];
    const float* Wproj = (const float*)d_in[8];
    const float* bproj = (const float*)d_in[9];

    float* out_x    = (float*)d_out;                       // (B,S,DIM)
    float* out_attn = out_x + (size_t)B_ * S_ * DIM_;      // (B,H,S,S)

    char* w = (char*)d_ws;
    bf16* qx_b  = (bf16*)(w + (size_t)0);          //  8 MiB
    bf16* kvx_b = (bf16*)(w + ((size_t)8  << 20)); //  8 MiB
    bf16* wq_b  = (bf16*)(w + ((size_t)16 << 20)); //  2 MiB
    bf16* wkv_b = (bf16*)(w + ((size_t)18 << 20)); //  4 MiB
    bf16* wpj_b = (bf16*)(w + ((size_t)22 << 20)); //  2 MiB
    bf16* qp    = (bf16*)(w + ((size_t)24 << 20)); //  8 MiB  (B,S,DIM)
    bf16* kvp   = (bf16*)(w + ((size_t)32 << 20)); // 16 MiB  (B,S,2*DIM)
    bf16* qr    = (bf16*)(w + ((size_t)48 << 20)); //  8 MiB  (B,H,S,HD)
    bf16* kr    = (bf16*)(w + ((size_t)56 << 20)); //  8 MiB
    bf16* vt    = (bf16*)(w + ((size_t)64 << 20)); //  8 MiB  (B,H,HD,S)
    bf16* ob    = (bf16*)(w + ((size_t)72 << 20)); //  8 MiB  (B,S,DIM)
    float* lpb  = (float*)(w + ((size_t)96 << 20)); // 32 MiB  (B,S,S) f32

    // all conversions + lp in one kernel (nt loads: inputs read exactly once)
    prep_kernel<<<10240, 256, 0, stream>>>(q_x, kv_x, Wq, Wkv, Wproj, maskp, prior,
                                           qx_b, kvx_b, wq_b, wkv_b, wpj_b, lpb);

    // projections: all 128x64 tiles, XCD-chunked 1D grids
    gemm_bt64<0, 0><<<512,  256, 0, stream>>>(qx_b,  wq_b,  qp,  nullptr, 4096, 1024, 1024);
    gemm_bt64<0, 0><<<1024, 256, 0, stream>>>(kvx_b, wkv_b, kvp, nullptr, 4096, 2048, 1024);

    // RoPE (q,k) + V transpose in one kernel
    rope_vt_kernel<<<5120, 256, 0, stream>>>(qp, kvp, q_fr, k_fr, qr, kr, vt);

    // fused attention: O + attn in one kernel (XCD-swizzled grid)
    attn_fused<<<1024, 256, 0, stream>>>(qr, kr, vt, lpb, out_attn, ob);

    // output projection: 128x64 tile, nt f32 stores
    gemm_bt64<1, 1><<<512, 256, 0, stream>>>(ob, wpj_b, out_x, bproj, 4096, 1024, 1024);
}